// Round 1
// baseline (546.603 us; speedup 1.0000x reference)
//
#include <hip/hip_runtime.h>
#include <math.h>

#define SS 112
#define HW (SS*SS)
#define NPIX (2*HW)   // B*S*S = 25088

__device__ __forceinline__ float wave_sum64(float v){
  #pragma unroll
  for (int m = 32; m; m >>= 1) v += __shfl_xor(v, m, 64);
  return v;
}

__device__ __forceinline__ float gelu_exact(float x){
  return 0.5f * x * (1.0f + erff(x * 0.7071067811865476f));
}

// OIHW (64,64,3,3) -> [tap][ic][oc]
__global__ __launch_bounds__(256) void k_transpose_w(const float* __restrict__ w,
                                                     float* __restrict__ wT){
  int idx = blockIdx.x * 256 + threadIdx.x;
  if (idx >= 64*64*9) return;
  int oc  = idx / (64*9);
  int rem = idx - oc*(64*9);
  int ic  = rem / 9;
  int tap = rem - ic*9;
  wT[(tap*64 + ic)*64 + oc] = w[idx];
}

// One wave handles 2 consecutive pixels (shares weight loads).
// lane = out-channel. conv(3x3) -> LayerNorm -> 1 or 2 projections.
__global__ __launch_bounds__(256) void k_conv_ln_proj(
    const float* __restrict__ x,      // (B,64,112,112)
    const float* __restrict__ wT,     // (9,64,64)
    const float* __restrict__ cb,     // (64,)
    const float* __restrict__ gamma, const float* __restrict__ beta,
    const float* __restrict__ Wa, const float* __restrict__ ba,
    const float* __restrict__ Wb, const float* __restrict__ bb,
    float* __restrict__ outa, float* __restrict__ outb,
    float* __restrict__ emb, int mode)
{
  __shared__ float nl[4][2][64];
  const int wid = threadIdx.x >> 6, lane = threadIdx.x & 63;
  const int pw = blockIdx.x * 4 + wid;
  const int p0 = pw * 2, p1 = p0 + 1;
  const int b0 = p0 / HW, r0 = p0 - b0*HW, i0 = r0 / SS, j0 = r0 - i0*SS;
  const int b1 = p1 / HW, r1 = p1 - b1*HW, i1 = r1 / SS, j1 = r1 - i1*SS;

  float acc0 = cb[lane];
  float acc1 = acc0;
  const float* xb0 = x + b0 * (64*HW);
  const float* xb1 = x + b1 * (64*HW);

  #pragma unroll
  for (int ky = 0; ky < 3; ++ky){
    #pragma unroll
    for (int kx = 0; kx < 3; ++kx){
      int yy0 = i0+ky-1, xx0 = j0+kx-1;
      int yy1 = i1+ky-1, xx1 = j1+kx-1;
      bool v0 = ((unsigned)yy0 < SS) && ((unsigned)xx0 < SS);
      bool v1 = ((unsigned)yy1 < SS) && ((unsigned)xx1 < SS);
      const float* wp  = wT + (ky*3+kx)*4096 + lane;
      const float* ip0 = xb0 + yy0*SS + xx0;
      const float* ip1 = xb1 + yy1*SS + xx1;
      if (v0 && v1){
        #pragma unroll 8
        for (int ic = 0; ic < 64; ++ic){
          float w = wp[ic*64];
          acc0 = fmaf(ip0[ic*HW], w, acc0);
          acc1 = fmaf(ip1[ic*HW], w, acc1);
        }
      } else if (v0){
        #pragma unroll 8
        for (int ic = 0; ic < 64; ++ic) acc0 = fmaf(ip0[ic*HW], wp[ic*64], acc0);
      } else if (v1){
        #pragma unroll 8
        for (int ic = 0; ic < 64; ++ic) acc1 = fmaf(ip1[ic*HW], wp[ic*64], acc1);
      }
    }
  }

  if (mode){
    emb[p0*64 + lane] = acc0;
    emb[p1*64 + lane] = acc1;
  }

  // LayerNorm over channels (wave reduction)
  float m0 = wave_sum64(acc0) * (1.f/64.f);
  float d0 = acc0 - m0;
  float v0 = wave_sum64(d0*d0) * (1.f/64.f);
  float n0 = d0 * rsqrtf(v0 + 1e-5f) * gamma[lane] + beta[lane];
  float m1 = wave_sum64(acc1) * (1.f/64.f);
  float d1 = acc1 - m1;
  float v1 = wave_sum64(d1*d1) * (1.f/64.f);
  float n1 = d1 * rsqrtf(v1 + 1e-5f) * gamma[lane] + beta[lane];

  nl[wid][0][lane] = n0;
  nl[wid][1][lane] = n1;
  __syncthreads();

  float a0 = ba[lane], a1 = a0;
  #pragma unroll 8
  for (int ic = 0; ic < 64; ++ic){
    float w = Wa[ic*64 + lane];
    a0 = fmaf(nl[wid][0][ic], w, a0);
    a1 = fmaf(nl[wid][1][ic], w, a1);
  }
  outa[p0*64 + lane] = a0;
  outa[p1*64 + lane] = a1;

  if (mode){
    float c0 = bb[lane], c1 = c0;
    #pragma unroll 8
    for (int ic = 0; ic < 64; ++ic){
      float w = Wb[ic*64 + lane];
      c0 = fmaf(nl[wid][0][ic], w, c0);
      c1 = fmaf(nl[wid][1][ic], w, c1);
    }
    outb[p0*64 + lane] = c0;
    outb[p1*64 + lane] = c1;
  }
}

// Neighborhood attention: wave = pixel, lane = h*16 + d.
__global__ __launch_bounds__(256) void k_natten(
    const float* __restrict__ q, const float* __restrict__ k,
    const float* __restrict__ v, const float* __restrict__ rpb,
    float* __restrict__ out)
{
  const int wid = threadIdx.x >> 6, lane = threadIdx.x & 63;
  const int p = blockIdx.x * 4 + wid;
  const int b = p / HW, r = p - b*HW, i = r / SS, j = r - i*SS;
  const int d = lane & 15, h = lane >> 4;
  const int si = min(max(i - 3, 0), SS - 7);
  const int sj = min(max(j - 3, 0), SS - 7);

  const float* kb = k + b * (HW*64);
  const float* vb = v + b * (HW*64);
  const float qr = q[p*64 + lane];
  const float* rh = rpb + h*169 + (si - i + 6)*13 + (sj - j + 6);

  float larr[4] = {-1e30f, -1e30f, -1e30f, -1e30f};
  #pragma unroll
  for (int n = 0; n < 49; ++n){
    int ky = n / 7, kx = n - ky*7;
    int np = (si+ky)*SS + (sj+kx);
    float t = qr * kb[np*64 + lane];
    t += __shfl_xor(t, 1, 64);
    t += __shfl_xor(t, 2, 64);
    t += __shfl_xor(t, 4, 64);
    t += __shfl_xor(t, 8, 64);
    t = t * 0.25f + rh[ky*13 + kx];
    if ((n & 15) == d) larr[n >> 4] = t;
  }

  float m = fmaxf(fmaxf(larr[0], larr[1]), fmaxf(larr[2], larr[3]));
  #pragma unroll
  for (int mm = 8; mm; mm >>= 1) m = fmaxf(m, __shfl_xor(m, mm, 64));

  float earr[4];
  #pragma unroll
  for (int s = 0; s < 4; ++s) earr[s] = expf(larr[s] - m); // -1e30 slots underflow to 0
  float esum = earr[0] + earr[1] + earr[2] + earr[3];
  #pragma unroll
  for (int mm = 8; mm; mm >>= 1) esum += __shfl_xor(esum, mm, 64);
  float inv = 1.0f / esum;

  float acc = 0.f;
  const int base = lane & 48;
  #pragma unroll
  for (int n = 0; n < 49; ++n){
    int ky = n / 7, kx = n - ky*7;
    int np = (si+ky)*SS + (sj+kx);
    float pn = __shfl(earr[n >> 4], base | (n & 15), 64);
    acc = fmaf(pn, vb[np*64 + lane], acc);
  }
  out[p*64 + lane] = acc * inv;
}

// Wo proj + residual + LN + MLP (exact GELU) + residual, store NCHW. 2 px/wave.
__global__ __launch_bounds__(256) void k_out_mlp(
    const float* __restrict__ ao, const float* __restrict__ emb,
    const float* __restrict__ Wo, const float* __restrict__ bo,
    const float* __restrict__ gn, const float* __restrict__ bn,
    const float* __restrict__ W1, const float* __restrict__ b1,
    const float* __restrict__ W2, const float* __restrict__ b2,
    float* __restrict__ out)
{
  __shared__ float s_a[4][2][64];
  __shared__ float s_y[4][2][64];
  __shared__ float s_h[4][2][128];
  const int wid = threadIdx.x >> 6, lane = threadIdx.x & 63;
  const int pw = blockIdx.x * 4 + wid;
  const int p0 = pw * 2, p1 = p0 + 1;

  s_a[wid][0][lane] = ao[p0*64 + lane];
  s_a[wid][1][lane] = ao[p1*64 + lane];
  __syncthreads();

  float att0 = bo[lane] + emb[p0*64 + lane];
  float att1 = bo[lane] + emb[p1*64 + lane];
  #pragma unroll 8
  for (int ic = 0; ic < 64; ++ic){
    float w = Wo[ic*64 + lane];
    att0 = fmaf(s_a[wid][0][ic], w, att0);
    att1 = fmaf(s_a[wid][1][ic], w, att1);
  }

  float m0 = wave_sum64(att0) * (1.f/64.f);
  float d0 = att0 - m0;
  float v0 = wave_sum64(d0*d0) * (1.f/64.f);
  float y0 = d0 * rsqrtf(v0 + 1e-5f) * gn[lane] + bn[lane];
  float m1 = wave_sum64(att1) * (1.f/64.f);
  float d1 = att1 - m1;
  float v1 = wave_sum64(d1*d1) * (1.f/64.f);
  float y1 = d1 * rsqrtf(v1 + 1e-5f) * gn[lane] + bn[lane];

  s_y[wid][0][lane] = y0;
  s_y[wid][1][lane] = y1;
  __syncthreads();

  float h00 = b1[lane], h01 = b1[lane + 64];
  float h10 = h00, h11 = h01;
  #pragma unroll 4
  for (int ic = 0; ic < 64; ++ic){
    float ya = s_y[wid][0][ic], yb = s_y[wid][1][ic];
    float wlo = W1[ic*128 + lane], whi = W1[ic*128 + 64 + lane];
    h00 = fmaf(ya, wlo, h00); h01 = fmaf(ya, whi, h01);
    h10 = fmaf(yb, wlo, h10); h11 = fmaf(yb, whi, h11);
  }
  s_h[wid][0][lane]      = gelu_exact(h00);
  s_h[wid][0][lane + 64] = gelu_exact(h01);
  s_h[wid][1][lane]      = gelu_exact(h10);
  s_h[wid][1][lane + 64] = gelu_exact(h11);
  __syncthreads();

  float x0 = b2[lane] + att0, x1 = b2[lane] + att1;
  #pragma unroll 8
  for (int jj = 0; jj < 128; ++jj){
    float w = W2[jj*64 + lane];
    x0 = fmaf(s_h[wid][0][jj], w, x0);
    x1 = fmaf(s_h[wid][1][jj], w, x1);
  }

  const int b0 = p0 / HW, ij0 = p0 - b0*HW;
  const int b1_ = p1 / HW, ij1 = p1 - b1_*HW;
  out[(b0*64  + lane)*HW + ij0] = x0;
  out[(b1_*64 + lane)*HW + ij1] = x1;
}

extern "C" void kernel_launch(void* const* d_in, const int* in_sizes, int n_in,
                              void* d_out, int out_size, void* d_ws, size_t ws_size,
                              hipStream_t stream) {
  const float* xq  = (const float*)d_in[0];
  const float* xkv = (const float*)d_in[1];
  const float* cws = (const float*)d_in[2];
  const float* cbs = (const float*)d_in[3];
  const float* cwl = (const float*)d_in[4];
  const float* cbl = (const float*)d_in[5];
  const float* g_s = (const float*)d_in[6];
  const float* b_s = (const float*)d_in[7];
  const float* g_l = (const float*)d_in[8];
  const float* b_l = (const float*)d_in[9];
  const float* Wq  = (const float*)d_in[10];
  const float* bq  = (const float*)d_in[11];
  const float* Wk  = (const float*)d_in[12];
  const float* bk  = (const float*)d_in[13];
  const float* Wv  = (const float*)d_in[14];
  const float* bv  = (const float*)d_in[15];
  const float* Wo  = (const float*)d_in[16];
  const float* bo  = (const float*)d_in[17];
  const float* rpb = (const float*)d_in[18];
  const float* g_n = (const float*)d_in[19];
  const float* b_n = (const float*)d_in[20];
  const float* W1  = (const float*)d_in[21];
  const float* b1  = (const float*)d_in[22];
  const float* W2  = (const float*)d_in[23];
  const float* b2  = (const float*)d_in[24];

  float* ws  = (float*)d_ws;
  float* wTs = ws;                    // 36864
  float* wTl = wTs + 36864;           // 36864
  float* q   = wTl + 36864;           // NPIX*64
  float* k   = q   + NPIX*64;
  float* v   = k   + NPIX*64;
  float* emb = v   + NPIX*64;
  float* aow = emb + NPIX*64;

  hipLaunchKernelGGL(k_transpose_w, dim3(144), dim3(256), 0, stream, cws, wTs);
  hipLaunchKernelGGL(k_transpose_w, dim3(144), dim3(256), 0, stream, cwl, wTl);

  hipLaunchKernelGGL(k_conv_ln_proj, dim3(NPIX/8), dim3(256), 0, stream,
      xq, wTs, cbs, g_s, b_s, Wq, bq, (const float*)nullptr, (const float*)nullptr,
      q, (float*)nullptr, (float*)nullptr, 0);

  hipLaunchKernelGGL(k_conv_ln_proj, dim3(NPIX/8), dim3(256), 0, stream,
      xkv, wTl, cbl, g_l, b_l, Wk, bk, Wv, bv,
      k, v, emb, 1);

  hipLaunchKernelGGL(k_natten, dim3(NPIX/4), dim3(256), 0, stream, q, k, v, rpb, aow);

  hipLaunchKernelGGL(k_out_mlp, dim3(NPIX/8), dim3(256), 0, stream,
      aow, emb, Wo, bo, g_n, b_n, W1, b1, W2, b2, (float*)d_out);
}

// Round 2
// 245.798 us; speedup vs baseline: 2.2238x; 2.2238x over previous
//
#include <hip/hip_runtime.h>
#include <math.h>

#define SS 112
#define HW (SS*SS)
#define NPIX (2*HW)   // B*S*S = 25088

typedef __bf16 v8bf __attribute__((ext_vector_type(8)));
typedef short  v8s  __attribute__((ext_vector_type(8)));
typedef float  v4f  __attribute__((ext_vector_type(4)));

__device__ __forceinline__ unsigned short f2bf(float f){
  unsigned u = __builtin_bit_cast(unsigned, f);
  u = (u + 0x7fffu + ((u >> 16) & 1u)) >> 16;
  return (unsigned short)u;
}
__device__ __forceinline__ float bf2f(unsigned short h){
  unsigned u = ((unsigned)h) << 16;
  return __builtin_bit_cast(float, u);
}
__device__ __forceinline__ v8bf zero8(){
  v8s z = {0,0,0,0,0,0,0,0};
  return __builtin_bit_cast(v8bf, z);
}
__device__ __forceinline__ float wave_sum64(float v){
  #pragma unroll
  for (int m = 32; m; m >>= 1) v += __shfl_xor(v, m, 64);
  return v;
}
__device__ __forceinline__ float gelu_exact(float x){
  return 0.5f * x * (1.0f + erff(x * 0.7071067811865476f));
}

// ---------------- prep: NCHW fp32 -> [pixel][c] bf16 (channels-last) --------
__global__ __launch_bounds__(256) void k_prep_x(const float* __restrict__ x,
                                                unsigned short* __restrict__ xT){
  __shared__ float tile[64][68];
  const int t = threadIdx.x;
  const int base = blockIdx.x * 64;      // 64 pixels per block, never crosses batch
  const int b = base / HW;
  const int r0 = base - b*HW;
  {
    const int c = t >> 2, xo = (t & 3) << 4;
    const float* src = x + ((size_t)(b*64 + c))*HW + r0 + xo;
    float4 v0 = ((const float4*)src)[0];
    float4 v1 = ((const float4*)src)[1];
    float4 v2 = ((const float4*)src)[2];
    float4 v3 = ((const float4*)src)[3];
    float* dst = &tile[c][xo];
    ((float4*)dst)[0] = v0; ((float4*)dst)[1] = v1;
    ((float4*)dst)[2] = v2; ((float4*)dst)[3] = v3;
  }
  __syncthreads();
  {
    const int px = t >> 2, co = (t & 3) << 4;
    union { unsigned short u[16]; uint4 q[2]; } pk;
    #pragma unroll
    for (int i = 0; i < 16; ++i) pk.u[i] = f2bf(tile[co + i][px]);
    uint4* dst = (uint4*)(xT + ((size_t)(base + px))*64 + co);
    dst[0] = pk.q[0]; dst[1] = pk.q[1];
  }
}

// ------------- prep: conv weights OIHW -> MFMA B-fragments ------------------
// WB[kk=0..17][tile=0..3][lane=0..63][i=0..7] bf16
// k = tap*64 + ic ; kk covers k in [kk*32, kk*32+32); lane i -> k = kk*32 + 8*(l>>4)+i
__global__ __launch_bounds__(256) void k_prep_wconv(const float* __restrict__ w,
                                                    unsigned short* __restrict__ WB){
  int idx = blockIdx.x*256 + threadIdx.x;       // 0..4607
  int lane = idx & 63, tslot = (idx >> 6) & 3, kk = idx >> 8;
  int tap = kk >> 1;
  int ic0 = ((kk & 1) << 5) + ((lane >> 4) << 3);
  int oc  = tslot*16 + (lane & 15);
  union { unsigned short u[8]; uint4 q; } pk;
  #pragma unroll
  for (int i = 0; i < 8; ++i) pk.u[i] = f2bf(w[(oc*64 + ic0 + i)*9 + tap]);
  ((uint4*)WB)[idx] = pk.q;
}

// ------------- prep: (64,64) linear weights -> MFMA B-fragments -------------
// WB[kk=0..1][tile=0..3][lane][8] ; element i -> k = kk*32 + 8*(l>>4)+i, col = tile*16+(l&15)
__global__ __launch_bounds__(256) void k_prep_wlin(const float* __restrict__ W,
                                                   unsigned short* __restrict__ WB){
  int idx = blockIdx.x*256 + threadIdx.x;       // 0..511
  int lane = idx & 63, tslot = (idx >> 6) & 3, kk = idx >> 8;
  int k0 = kk*32 + ((lane >> 4) << 3);
  int oc = tslot*16 + (lane & 15);
  union { unsigned short u[8]; uint4 q; } pk;
  #pragma unroll
  for (int i = 0; i < 8; ++i) pk.u[i] = f2bf(W[(k0 + i)*64 + oc]);
  ((uint4*)WB)[idx] = pk.q;
}

// --------- fused conv(3x3, MFMA) + LayerNorm + projection(s) ---------------
// 1 wave per block; 32 pixels (2 M-tiles of 16) x 64 oc per wave.
__global__ __launch_bounds__(64) void k_conv_mfma(
    const unsigned short* __restrict__ xT, const unsigned short* __restrict__ WBc,
    const float* __restrict__ cb, const float* __restrict__ gamma,
    const float* __restrict__ beta,
    const unsigned short* __restrict__ WBa, const float* __restrict__ ba,
    const unsigned short* __restrict__ WBb, const float* __restrict__ bb,
    unsigned short* __restrict__ outa, unsigned short* __restrict__ outb,
    float* __restrict__ emb, int mode)
{
  __shared__ unsigned short nlds[32*64];
  const int l = threadIdx.x;
  const int g = l >> 4, c = l & 15;
  const int P0 = blockIdx.x * 32;

  int py[2], pxx[2], pb64[2];
  #pragma unroll
  for (int m = 0; m < 2; ++m){
    int p = P0 + m*16 + c;          // A-row pixel for this lane
    int b = p / HW, r = p - b*HW;
    py[m] = r / SS; pxx[m] = r - py[m]*SS; pb64[m] = b*HW;
  }

  float cbv[4], gv[4], bev[4];
  #pragma unroll
  for (int t = 0; t < 4; ++t){
    cbv[t] = cb[c + 16*t]; gv[t] = gamma[c + 16*t]; bev[t] = beta[c + 16*t];
  }

  v4f acc[2][4];
  #pragma unroll
  for (int m = 0; m < 2; ++m)
    #pragma unroll
    for (int t = 0; t < 4; ++t)
      acc[m][t] = (v4f){cbv[t], cbv[t], cbv[t], cbv[t]};

  const int icg = g << 3;
  #pragma unroll
  for (int kk = 0; kk < 18; ++kk){
    const int tap = kk >> 1;
    const int dy = tap/3 - 1, dx = tap - (tap/3)*3 - 1;
    const int icof = ((kk & 1) << 5) + icg;
    v8bf a[2];
    #pragma unroll
    for (int m = 0; m < 2; ++m){
      int yy = py[m] + dy, xx = pxx[m] + dx;
      bool ok = ((unsigned)yy < SS) && ((unsigned)xx < SS);
      v8bf av = zero8();
      if (ok) av = *(const v8bf*)(xT + ((size_t)(pb64[m] + yy*SS + xx))*64 + icof);
      a[m] = av;
    }
    #pragma unroll
    for (int t = 0; t < 4; ++t){
      v8bf bfr = *(const v8bf*)(WBc + ((size_t)((kk*4 + t)*64 + l))*8);
      acc[0][t] = __builtin_amdgcn_mfma_f32_16x16x32_bf16(a[0], bfr, acc[0][t], 0, 0, 0);
      acc[1][t] = __builtin_amdgcn_mfma_f32_16x16x32_bf16(a[1], bfr, acc[1][t], 0, 0, 0);
    }
  }

  if (mode){
    #pragma unroll
    for (int m = 0; m < 2; ++m)
      #pragma unroll
      for (int t = 0; t < 4; ++t)
        #pragma unroll
        for (int r = 0; r < 4; ++r)
          emb[((size_t)(P0 + m*16 + 4*g + r))*64 + c + 16*t] = acc[m][t][r];
  }

  // LayerNorm per pixel (pixel = P0 + m*16 + 4*g + r, channels across 16-lane group x 4 tiles)
  #pragma unroll
  for (int m = 0; m < 2; ++m){
    float mean[4], inv[4];
    #pragma unroll
    for (int r = 0; r < 4; ++r){
      float s = acc[m][0][r] + acc[m][1][r] + acc[m][2][r] + acc[m][3][r];
      s += __shfl_xor(s, 1, 64); s += __shfl_xor(s, 2, 64);
      s += __shfl_xor(s, 4, 64); s += __shfl_xor(s, 8, 64);
      mean[r] = s * (1.f/64.f);
      float d0 = acc[m][0][r] - mean[r], d1 = acc[m][1][r] - mean[r];
      float d2 = acc[m][2][r] - mean[r], d3 = acc[m][3][r] - mean[r];
      float vs = d0*d0 + d1*d1 + d2*d2 + d3*d3;
      vs += __shfl_xor(vs, 1, 64); vs += __shfl_xor(vs, 2, 64);
      vs += __shfl_xor(vs, 4, 64); vs += __shfl_xor(vs, 8, 64);
      inv[r] = rsqrtf(vs * (1.f/64.f) + 1e-5f);
    }
    #pragma unroll
    for (int t = 0; t < 4; ++t){
      int c16 = 2*t + (c >> 3);
      #pragma unroll
      for (int r = 0; r < 4; ++r){
        int row = m*16 + 4*g + r;
        float n = (acc[m][t][r] - mean[r]) * inv[r] * gv[t] + bev[t];
        nlds[row*64 + (((c16 ^ (row & 7)) << 3) | (c & 7))] = f2bf(n);
      }
    }
  }
  __syncthreads();

  // projection(s): [32 x 64] @ [64 x 64]
  #pragma unroll
  for (int which = 0; which < 2; ++which){
    if (which == 1 && !mode) break;
    const unsigned short* WB = which ? WBb : WBa;
    const float* bias        = which ? bb  : ba;
    unsigned short* outp     = which ? outb : outa;

    float pb[4];
    #pragma unroll
    for (int t = 0; t < 4; ++t) pb[t] = bias[c + 16*t];
    v4f pa[2][4];
    #pragma unroll
    for (int m = 0; m < 2; ++m)
      #pragma unroll
      for (int t = 0; t < 4; ++t)
        pa[m][t] = (v4f){pb[t], pb[t], pb[t], pb[t]};

    #pragma unroll
    for (int kk = 0; kk < 2; ++kk){
      v8bf av[2];
      #pragma unroll
      for (int m = 0; m < 2; ++m){
        int row = m*16 + c;
        av[m] = *(const v8bf*)(nlds + row*64 + (((kk*4 + g) ^ (c & 7)) << 3));
      }
      #pragma unroll
      for (int t = 0; t < 4; ++t){
        v8bf bfr = *(const v8bf*)(WB + ((size_t)((kk*4 + t)*64 + l))*8);
        pa[0][t] = __builtin_amdgcn_mfma_f32_16x16x32_bf16(av[0], bfr, pa[0][t], 0, 0, 0);
        pa[1][t] = __builtin_amdgcn_mfma_f32_16x16x32_bf16(av[1], bfr, pa[1][t], 0, 0, 0);
      }
    }
    #pragma unroll
    for (int m = 0; m < 2; ++m)
      #pragma unroll
      for (int t = 0; t < 4; ++t)
        #pragma unroll
        for (int r = 0; r < 4; ++r)
          outp[((size_t)(P0 + m*16 + 4*g + r))*64 + c + 16*t] = f2bf(pa[m][t][r]);
  }
}

// ---------------- neighborhood attention (bf16 q/k/v) -----------------------
__global__ __launch_bounds__(256) void k_natten(
    const unsigned short* __restrict__ q, const unsigned short* __restrict__ k,
    const unsigned short* __restrict__ v, const float* __restrict__ rpb,
    float* __restrict__ out)
{
  const int wid = threadIdx.x >> 6, lane = threadIdx.x & 63;
  const int p = blockIdx.x * 4 + wid;
  const int b = p / HW, r = p - b*HW, i = r / SS, j = r - i*SS;
  const int d = lane & 15, h = lane >> 4;
  const int si = min(max(i - 3, 0), SS - 7);
  const int sj = min(max(j - 3, 0), SS - 7);

  const unsigned short* kb = k + (size_t)b * (HW*64);
  const unsigned short* vb = v + (size_t)b * (HW*64);
  const float qr = bf2f(q[(size_t)p*64 + lane]);
  const float* rh = rpb + h*169 + (si - i + 6)*13 + (sj - j + 6);

  float larr[4] = {-1e30f, -1e30f, -1e30f, -1e30f};
  #pragma unroll
  for (int n = 0; n < 49; ++n){
    int ky = n / 7, kx = n - ky*7;
    int np = (si+ky)*SS + (sj+kx);
    float t = qr * bf2f(kb[(size_t)np*64 + lane]);
    t += __shfl_xor(t, 1, 64);
    t += __shfl_xor(t, 2, 64);
    t += __shfl_xor(t, 4, 64);
    t += __shfl_xor(t, 8, 64);
    t = t * 0.25f + rh[ky*13 + kx];
    if ((n & 15) == d) larr[n >> 4] = t;
  }

  float m = fmaxf(fmaxf(larr[0], larr[1]), fmaxf(larr[2], larr[3]));
  #pragma unroll
  for (int mm = 8; mm; mm >>= 1) m = fmaxf(m, __shfl_xor(m, mm, 64));

  float earr[4];
  #pragma unroll
  for (int s = 0; s < 4; ++s) earr[s] = expf(larr[s] - m);
  float esum = earr[0] + earr[1] + earr[2] + earr[3];
  #pragma unroll
  for (int mm = 8; mm; mm >>= 1) esum += __shfl_xor(esum, mm, 64);
  float inv = 1.0f / esum;

  float acc = 0.f;
  const int base = lane & 48;
  #pragma unroll
  for (int n = 0; n < 49; ++n){
    int ky = n / 7, kx = n - ky*7;
    int np = (si+ky)*SS + (sj+kx);
    float pn = __shfl(earr[n >> 4], base | (n & 15), 64);
    acc = fmaf(pn, bf2f(vb[(size_t)np*64 + lane]), acc);
  }
  out[(size_t)p*64 + lane] = acc * inv;
}

// ------- Wo proj + residual + LN + MLP (exact GELU) + residual, NCHW -------
__global__ __launch_bounds__(256) void k_out_mlp(
    const float* __restrict__ ao, const float* __restrict__ emb,
    const float* __restrict__ Wo, const float* __restrict__ bo,
    const float* __restrict__ gn, const float* __restrict__ bn,
    const float* __restrict__ W1, const float* __restrict__ b1,
    const float* __restrict__ W2, const float* __restrict__ b2,
    float* __restrict__ out)
{
  __shared__ float s_a[4][2][64];
  __shared__ float s_y[4][2][64];
  __shared__ float s_h[4][2][128];
  const int wid = threadIdx.x >> 6, lane = threadIdx.x & 63;
  const int pw = blockIdx.x * 4 + wid;
  const int p0 = pw * 2, p1 = p0 + 1;

  s_a[wid][0][lane] = ao[p0*64 + lane];
  s_a[wid][1][lane] = ao[p1*64 + lane];
  __syncthreads();

  float att0 = bo[lane] + emb[p0*64 + lane];
  float att1 = bo[lane] + emb[p1*64 + lane];
  #pragma unroll 8
  for (int ic = 0; ic < 64; ++ic){
    float w = Wo[ic*64 + lane];
    att0 = fmaf(s_a[wid][0][ic], w, att0);
    att1 = fmaf(s_a[wid][1][ic], w, att1);
  }

  float m0 = wave_sum64(att0) * (1.f/64.f);
  float d0 = att0 - m0;
  float v0 = wave_sum64(d0*d0) * (1.f/64.f);
  float y0 = d0 * rsqrtf(v0 + 1e-5f) * gn[lane] + bn[lane];
  float m1 = wave_sum64(att1) * (1.f/64.f);
  float d1 = att1 - m1;
  float v1 = wave_sum64(d1*d1) * (1.f/64.f);
  float y1 = d1 * rsqrtf(v1 + 1e-5f) * gn[lane] + bn[lane];

  s_y[wid][0][lane] = y0;
  s_y[wid][1][lane] = y1;
  __syncthreads();

  float h00 = b1[lane], h01 = b1[lane + 64];
  float h10 = h00, h11 = h01;
  #pragma unroll 4
  for (int ic = 0; ic < 64; ++ic){
    float ya = s_y[wid][0][ic], yb = s_y[wid][1][ic];
    float wlo = W1[ic*128 + lane], whi = W1[ic*128 + 64 + lane];
    h00 = fmaf(ya, wlo, h00); h01 = fmaf(ya, whi, h01);
    h10 = fmaf(yb, wlo, h10); h11 = fmaf(yb, whi, h11);
  }
  s_h[wid][0][lane]      = gelu_exact(h00);
  s_h[wid][0][lane + 64] = gelu_exact(h01);
  s_h[wid][1][lane]      = gelu_exact(h10);
  s_h[wid][1][lane + 64] = gelu_exact(h11);
  __syncthreads();

  float x0 = b2[lane] + att0, x1 = b2[lane] + att1;
  #pragma unroll 8
  for (int jj = 0; jj < 128; ++jj){
    float w = W2[jj*64 + lane];
    x0 = fmaf(s_h[wid][0][jj], w, x0);
    x1 = fmaf(s_h[wid][1][jj], w, x1);
  }

  const int b0 = p0 / HW, ij0 = p0 - b0*HW;
  const int b1_ = p1 / HW, ij1 = p1 - b1_*HW;
  out[(b0*64  + lane)*HW + ij0] = x0;
  out[(b1_*64 + lane)*HW + ij1] = x1;
}

extern "C" void kernel_launch(void* const* d_in, const int* in_sizes, int n_in,
                              void* d_out, int out_size, void* d_ws, size_t ws_size,
                              hipStream_t stream) {
  const float* xq  = (const float*)d_in[0];
  const float* xkv = (const float*)d_in[1];
  const float* cws = (const float*)d_in[2];
  const float* cbs = (const float*)d_in[3];
  const float* cwl = (const float*)d_in[4];
  const float* cbl = (const float*)d_in[5];
  const float* g_s = (const float*)d_in[6];
  const float* b_s = (const float*)d_in[7];
  const float* g_l = (const float*)d_in[8];
  const float* b_l = (const float*)d_in[9];
  const float* Wq  = (const float*)d_in[10];
  const float* bq  = (const float*)d_in[11];
  const float* Wk  = (const float*)d_in[12];
  const float* bk  = (const float*)d_in[13];
  const float* Wv  = (const float*)d_in[14];
  const float* bv  = (const float*)d_in[15];
  const float* Wo  = (const float*)d_in[16];
  const float* bo  = (const float*)d_in[17];
  const float* rpb = (const float*)d_in[18];
  const float* g_n = (const float*)d_in[19];
  const float* b_n = (const float*)d_in[20];
  const float* W1  = (const float*)d_in[21];
  const float* b1  = (const float*)d_in[22];
  const float* W2  = (const float*)d_in[23];
  const float* b2  = (const float*)d_in[24];

  unsigned short* xTq  = (unsigned short*)d_ws;          // NPIX*64
  unsigned short* xTkv = xTq  + (size_t)NPIX*64;
  unsigned short* WBs  = xTkv + (size_t)NPIX*64;         // 36864
  unsigned short* WBl  = WBs  + 36864;
  unsigned short* WBq  = WBl  + 36864;                   // 4096 each
  unsigned short* WBk  = WBq  + 4096;
  unsigned short* WBv  = WBk  + 4096;
  unsigned short* qb   = WBv  + 4096;                    // NPIX*64 bf16
  unsigned short* kb   = qb   + (size_t)NPIX*64;
  unsigned short* vb   = kb   + (size_t)NPIX*64;
  float* emb = (float*)(vb + (size_t)NPIX*64);           // NPIX*64 f32
  float* aow = emb + (size_t)NPIX*64;

  hipLaunchKernelGGL(k_prep_x, dim3(NPIX/64), dim3(256), 0, stream, xq,  xTq);
  hipLaunchKernelGGL(k_prep_x, dim3(NPIX/64), dim3(256), 0, stream, xkv, xTkv);
  hipLaunchKernelGGL(k_prep_wconv, dim3(18), dim3(256), 0, stream, cws, WBs);
  hipLaunchKernelGGL(k_prep_wconv, dim3(18), dim3(256), 0, stream, cwl, WBl);
  hipLaunchKernelGGL(k_prep_wlin, dim3(2), dim3(256), 0, stream, Wq, WBq);
  hipLaunchKernelGGL(k_prep_wlin, dim3(2), dim3(256), 0, stream, Wk, WBk);
  hipLaunchKernelGGL(k_prep_wlin, dim3(2), dim3(256), 0, stream, Wv, WBv);

  hipLaunchKernelGGL(k_conv_mfma, dim3(NPIX/32), dim3(64), 0, stream,
      xTq, WBs, cbs, g_s, b_s, WBq, bq, (const unsigned short*)nullptr, (const float*)nullptr,
      qb, (unsigned short*)nullptr, (float*)nullptr, 0);

  hipLaunchKernelGGL(k_conv_mfma, dim3(NPIX/32), dim3(64), 0, stream,
      xTkv, WBl, cbl, g_l, b_l, WBk, bk, WBv, bv,
      kb, vb, emb, 1);

  hipLaunchKernelGGL(k_natten, dim3(NPIX/4), dim3(256), 0, stream, qb, kb, vb, rpb, aow);

  hipLaunchKernelGGL(k_out_mlp, dim3(NPIX/8), dim3(256), 0, stream,
      aow, emb, Wo, bo, g_n, b_n, W1, b1, W2, b2, (float*)d_out);
}

// Round 4
// 122.159 us; speedup vs baseline: 4.4745x; 2.0121x over previous
//
#include <hip/hip_runtime.h>
#include <math.h>

#define SS 112
#define HW (SS*SS)
#define NPIX (2*HW)   // B*S*S = 25088

typedef __bf16 v8bf __attribute__((ext_vector_type(8)));
typedef short  v8s  __attribute__((ext_vector_type(8)));
typedef float  v4f  __attribute__((ext_vector_type(4)));

__device__ __forceinline__ unsigned short f2bf(float f){
  unsigned u = __builtin_bit_cast(unsigned, f);
  u = (u + 0x7fffu + ((u >> 16) & 1u)) >> 16;
  return (unsigned short)u;
}
__device__ __forceinline__ v8bf zero8(){
  v8s z = {0,0,0,0,0,0,0,0};
  return __builtin_bit_cast(v8bf, z);
}
__device__ __forceinline__ float gelu_exact(float x){
  return 0.5f * x * (1.0f + erff(x * 0.7071067811865476f));
}

// ---------------- prep: NCHW fp32 -> [pixel][c] bf16 (channels-last) --------
__global__ __launch_bounds__(256) void k_prep_x(const float* __restrict__ x,
                                                unsigned short* __restrict__ xT){
  __shared__ float tile[64][68];
  const int t = threadIdx.x;
  const int base = blockIdx.x * 64;
  const int b = base / HW;
  const int r0 = base - b*HW;
  {
    const int c = t >> 2, xo = (t & 3) << 4;
    const float* src = x + ((size_t)(b*64 + c))*HW + r0 + xo;
    float4 v0 = ((const float4*)src)[0];
    float4 v1 = ((const float4*)src)[1];
    float4 v2 = ((const float4*)src)[2];
    float4 v3 = ((const float4*)src)[3];
    float* dst = &tile[c][xo];
    ((float4*)dst)[0] = v0; ((float4*)dst)[1] = v1;
    ((float4*)dst)[2] = v2; ((float4*)dst)[3] = v3;
  }
  __syncthreads();
  {
    const int px = t >> 2, co = (t & 3) << 4;
    union { unsigned short u[16]; uint4 q[2]; } pk;
    #pragma unroll
    for (int i = 0; i < 16; ++i) pk.u[i] = f2bf(tile[co + i][px]);
    uint4* dst = (uint4*)(xT + ((size_t)(base + px))*64 + co);
    dst[0] = pk.q[0]; dst[1] = pk.q[1];
  }
}

// ------------- prep: conv weights OIHW -> MFMA B-fragments ------------------
__global__ __launch_bounds__(256) void k_prep_wconv(const float* __restrict__ w,
                                                    unsigned short* __restrict__ WB){
  int idx = blockIdx.x*256 + threadIdx.x;       // 0..4607
  int lane = idx & 63, tslot = (idx >> 6) & 3, kk = idx >> 8;
  int tap = kk >> 1;
  int ic0 = ((kk & 1) << 5) + ((lane >> 4) << 3);
  int oc  = tslot*16 + (lane & 15);
  union { unsigned short u[8]; uint4 q; } pk;
  #pragma unroll
  for (int i = 0; i < 8; ++i) pk.u[i] = f2bf(w[(oc*64 + ic0 + i)*9 + tap]);
  ((uint4*)WB)[idx] = pk.q;
}

// ------------- prep: (K,N) linear weights -> MFMA B-fragments ---------------
// WB[kk][tile][lane][8]; elem i -> k = kk*32 + 8*(l>>4)+i, col = tile*16+(l&15)
__global__ __launch_bounds__(256) void k_prep_wlinG(const float* __restrict__ W,
                                                    unsigned short* __restrict__ WB,
                                                    int N, int total){
  int idx = blockIdx.x*256 + threadIdx.x;
  if (idx >= total) return;
  int lane = idx & 63;
  int tmp = idx >> 6;
  int tiles = N >> 4;
  int tslot = tmp % tiles;
  int kk = tmp / tiles;
  int k0 = kk*32 + ((lane >> 4) << 3);
  int oc = tslot*16 + (lane & 15);
  union { unsigned short u[8]; uint4 q; } pk;
  #pragma unroll
  for (int i = 0; i < 8; ++i) pk.u[i] = f2bf(W[(size_t)(k0 + i)*N + oc]);
  ((uint4*)WB)[idx] = pk.q;
}

// ------------- prep: rpb scaled by 1/ln2 ------------------------------------
__global__ __launch_bounds__(256) void k_prep_rpb(const float* __restrict__ rpb,
                                                  float* __restrict__ rpb2){
  int idx = blockIdx.x*256 + threadIdx.x;
  if (idx < 4*169) rpb2[idx] = rpb[idx] * 1.4426950408889634f;
}

// --------- fused conv(3x3, MFMA) + LayerNorm + projection(s) ---------------
__global__ __launch_bounds__(64) void k_conv_mfma(
    const unsigned short* __restrict__ xT, const unsigned short* __restrict__ WBc,
    const float* __restrict__ cb, const float* __restrict__ gamma,
    const float* __restrict__ beta,
    const unsigned short* __restrict__ WBa, const float* __restrict__ ba,
    const unsigned short* __restrict__ WBb, const float* __restrict__ bb,
    unsigned short* __restrict__ outa, unsigned short* __restrict__ outb,
    float* __restrict__ emb, int mode)
{
  __shared__ unsigned short nlds[32*64];
  const int l = threadIdx.x;
  const int g = l >> 4, c = l & 15;
  const int P0 = blockIdx.x * 32;

  int py[2], pxx[2], pb64[2];
  #pragma unroll
  for (int m = 0; m < 2; ++m){
    int p = P0 + m*16 + c;
    int b = p / HW, r = p - b*HW;
    py[m] = r / SS; pxx[m] = r - py[m]*SS; pb64[m] = b*HW;
  }

  float cbv[4], gv[4], bev[4];
  #pragma unroll
  for (int t = 0; t < 4; ++t){
    cbv[t] = cb[c + 16*t]; gv[t] = gamma[c + 16*t]; bev[t] = beta[c + 16*t];
  }

  v4f acc[2][4];
  #pragma unroll
  for (int m = 0; m < 2; ++m)
    #pragma unroll
    for (int t = 0; t < 4; ++t)
      acc[m][t] = (v4f){cbv[t], cbv[t], cbv[t], cbv[t]};

  const int icg = g << 3;
  #pragma unroll
  for (int kk = 0; kk < 18; ++kk){
    const int tap = kk >> 1;
    const int dy = tap/3 - 1, dx = tap - (tap/3)*3 - 1;
    const int icof = ((kk & 1) << 5) + icg;
    v8bf a[2];
    #pragma unroll
    for (int m = 0; m < 2; ++m){
      int yy = py[m] + dy, xx = pxx[m] + dx;
      bool ok = ((unsigned)yy < SS) && ((unsigned)xx < SS);
      v8bf av = zero8();
      if (ok) av = *(const v8bf*)(xT + ((size_t)(pb64[m] + yy*SS + xx))*64 + icof);
      a[m] = av;
    }
    #pragma unroll
    for (int t = 0; t < 4; ++t){
      v8bf bfr = *(const v8bf*)(WBc + ((size_t)((kk*4 + t)*64 + l))*8);
      acc[0][t] = __builtin_amdgcn_mfma_f32_16x16x32_bf16(a[0], bfr, acc[0][t], 0, 0, 0);
      acc[1][t] = __builtin_amdgcn_mfma_f32_16x16x32_bf16(a[1], bfr, acc[1][t], 0, 0, 0);
    }
  }

  if (mode){
    #pragma unroll
    for (int m = 0; m < 2; ++m)
      #pragma unroll
      for (int t = 0; t < 4; ++t)
        #pragma unroll
        for (int r = 0; r < 4; ++r)
          emb[((size_t)(P0 + m*16 + 4*g + r))*64 + c + 16*t] = acc[m][t][r];
  }

  #pragma unroll
  for (int m = 0; m < 2; ++m){
    float mean[4], inv[4];
    #pragma unroll
    for (int r = 0; r < 4; ++r){
      float s = acc[m][0][r] + acc[m][1][r] + acc[m][2][r] + acc[m][3][r];
      s += __shfl_xor(s, 1, 64); s += __shfl_xor(s, 2, 64);
      s += __shfl_xor(s, 4, 64); s += __shfl_xor(s, 8, 64);
      mean[r] = s * (1.f/64.f);
      float d0 = acc[m][0][r] - mean[r], d1 = acc[m][1][r] - mean[r];
      float d2 = acc[m][2][r] - mean[r], d3 = acc[m][3][r] - mean[r];
      float vs = d0*d0 + d1*d1 + d2*d2 + d3*d3;
      vs += __shfl_xor(vs, 1, 64); vs += __shfl_xor(vs, 2, 64);
      vs += __shfl_xor(vs, 4, 64); vs += __shfl_xor(vs, 8, 64);
      inv[r] = rsqrtf(vs * (1.f/64.f) + 1e-5f);
    }
    #pragma unroll
    for (int t = 0; t < 4; ++t){
      int c16 = 2*t + (c >> 3);
      #pragma unroll
      for (int r = 0; r < 4; ++r){
        int row = m*16 + 4*g + r;
        float n = (acc[m][t][r] - mean[r]) * inv[r] * gv[t] + bev[t];
        nlds[row*64 + (((c16 ^ (row & 7)) << 3) | (c & 7))] = f2bf(n);
      }
    }
  }
  __syncthreads();

  #pragma unroll
  for (int which = 0; which < 2; ++which){
    if (which == 1 && !mode) break;
    const unsigned short* WB = which ? WBb : WBa;
    const float* bias        = which ? bb  : ba;
    unsigned short* outp     = which ? outb : outa;

    float pb[4];
    #pragma unroll
    for (int t = 0; t < 4; ++t) pb[t] = bias[c + 16*t];
    v4f pa[2][4];
    #pragma unroll
    for (int m = 0; m < 2; ++m)
      #pragma unroll
      for (int t = 0; t < 4; ++t)
        pa[m][t] = (v4f){pb[t], pb[t], pb[t], pb[t]};

    #pragma unroll
    for (int kk = 0; kk < 2; ++kk){
      v8bf av[2];
      #pragma unroll
      for (int m = 0; m < 2; ++m){
        int row = m*16 + c;
        av[m] = *(const v8bf*)(nlds + row*64 + (((kk*4 + g) ^ (c & 7)) << 3));
      }
      #pragma unroll
      for (int t = 0; t < 4; ++t){
        v8bf bfr = *(const v8bf*)(WB + ((size_t)((kk*4 + t)*64 + l))*8);
        pa[0][t] = __builtin_amdgcn_mfma_f32_16x16x32_bf16(av[0], bfr, pa[0][t], 0, 0, 0);
        pa[1][t] = __builtin_amdgcn_mfma_f32_16x16x32_bf16(av[1], bfr, pa[1][t], 0, 0, 0);
      }
    }
    #pragma unroll
    for (int m = 0; m < 2; ++m)
      #pragma unroll
      for (int t = 0; t < 4; ++t)
        #pragma unroll
        for (int r = 0; r < 4; ++r)
          outp[((size_t)(P0 + m*16 + 4*g + r))*64 + c + 16*t] = f2bf(pa[m][t][r]);
  }
}

// ---------------- neighborhood attention via MFMA ---------------------------
// Block = 4 waves = 4 heads of one 16-pixel row segment.
// Key window: 7 rows (ky=t) x 32 cols (kx, 22 real), flattened n = ky*32+kx.
// QK tile tau: A-row slot rho holds key kx = 8*(rho>>2) + 4*(tau&1) + (rho&3),
// ky = tau>>1. This makes the QK C-fragment exactly the PV A-fragment.
__global__ __launch_bounds__(256) void k_natten_mfma(
    const unsigned short* __restrict__ q, const unsigned short* __restrict__ k,
    const unsigned short* __restrict__ v, const float* __restrict__ rpb2,
    unsigned short* __restrict__ out)
{
  const int l = threadIdx.x & 63;
  const int h = threadIdx.x >> 6;
  const int p0 = blockIdx.x * 16;
  const int b = p0 / HW, r0 = p0 - b*HW;
  const int i = r0 / SS, j0 = r0 - i*SS;
  const int c = l & 15, g = l >> 4;

  const int si  = min(max(i - 3, 0), SS - 7);
  const int sjm = min(max(j0 - 3, 0), SS - 22);
  const int oi  = si - i + 6;                 // bias row offset
  const int pbase = b*HW;

  const int j   = j0 + c;
  const int sjp = min(max(j - 3, 0), SS - 7);
  const int adj = 8*g + (sjm - sjp);          // valid: 0 <= adj+cc <= 6
  const int e8  = 8*g + (sjm - j + 6);        // rj = e8 + cc

  // Q B-frag: col = pixel c, k = dh = 8g+i (g>=2 zero-padded)
  v8bf bq = zero8();
  if (g < 2) bq = *(const v8bf*)(q + (size_t)(p0 + c)*64 + h*16 + 8*g);

  // ---- QK^T: 14 MFMA tiles -> 56 logits/lane ----
  float lt[14][4];
  const int arow = 8*(c >> 2) + (c & 3);
  #pragma unroll
  for (int tau = 0; tau < 14; ++tau){
    const int t = tau >> 1;
    int kpix = pbase + (si + t)*SS + sjm + arow + 4*(tau & 1);
    kpix = min(kpix, 2*HW - 1);
    v8bf ak = zero8();
    if (g < 2) ak = *(const v8bf*)(k + (size_t)kpix*64 + h*16 + 8*g);
    v4f a0 = {0.f,0.f,0.f,0.f};
    a0 = __builtin_amdgcn_mfma_f32_16x16x32_bf16(ak, bq, a0, 0, 0, 0);
    lt[tau][0]=a0[0]; lt[tau][1]=a0[1]; lt[tau][2]=a0[2]; lt[tau][3]=a0[3];
  }

  // ---- mask + bias (log2 domain) + softmax ----
  const float SC = 0.3606737602222409f;       // 0.25/ln2
  float mx = -3e38f;
  #pragma unroll
  for (int tau = 0; tau < 14; ++tau){
    const int t = tau >> 1;
    const float* bt = rpb2 + h*169 + (t + oi)*13;
    #pragma unroll
    for (int r = 0; r < 4; ++r){
      const int cc = 4*(tau & 1) + r;
      int rj = min(max(e8 + cc, 0), 12);
      float bias = bt[rj];
      bool valid = (unsigned)(adj + cc) <= 6u;
      float lg = fmaf(lt[tau][r], SC, bias);
      lt[tau][r] = valid ? lg : -1e30f;
      mx = fmaxf(mx, lt[tau][r]);
    }
  }
  mx = fmaxf(mx, __shfl_xor(mx, 16, 64));
  mx = fmaxf(mx, __shfl_xor(mx, 32, 64));
  float es = 0.f;
  #pragma unroll
  for (int tau = 0; tau < 14; ++tau)
    #pragma unroll
    for (int r = 0; r < 4; ++r){
      float p = exp2f(lt[tau][r] - mx);
      lt[tau][r] = p;
      es += p;
    }
  es += __shfl_xor(es, 16, 64);
  es += __shfl_xor(es, 32, 64);
  const float inv = 1.0f / es;

  // ---- PV: 7 MFMA tiles (K=32 keys each) ----
  v4f oacc = {0.f,0.f,0.f,0.f};
  #pragma unroll
  for (int t = 0; t < 7; ++t){
    union { unsigned short u[8]; v8bf bf; } pa;
    #pragma unroll
    for (int r = 0; r < 4; ++r){
      pa.u[r]     = f2bf(lt[2*t][r]   * inv);
      pa.u[4 + r] = f2bf(lt[2*t+1][r] * inv);
    }
    int vpixb = pbase + (si + t)*SS + sjm + 8*g;
    vpixb = min(vpixb, 2*HW - 8);
    const unsigned short* vp = v + (size_t)vpixb*64 + h*16 + c;
    union { unsigned short u[8]; v8bf bf; } bv;
    #pragma unroll
    for (int ii = 0; ii < 8; ++ii) bv.u[ii] = vp[ii*64];
    oacc = __builtin_amdgcn_mfma_f32_16x16x32_bf16(pa.bf, bv.bf, oacc, 0, 0, 0);
  }

  // C: row = pixel 4g+r, col = dh = c
  #pragma unroll
  for (int r = 0; r < 4; ++r)
    out[(size_t)(p0 + 4*g + r)*64 + h*16 + c] = f2bf(oacc[r]);
}

// ------- Wo proj + residual + LN + MLP (exact GELU) + residual, NCHW -------
// 1 wave per block, 32 pixels. All GEMMs on MFMA.
__global__ __launch_bounds__(64) void k_out_mfma(
    const unsigned short* __restrict__ ao, const float* __restrict__ emb,
    const unsigned short* __restrict__ WBo, const float* __restrict__ bo,
    const float* __restrict__ gn, const float* __restrict__ bn,
    const unsigned short* __restrict__ WB1, const float* __restrict__ b1,
    const unsigned short* __restrict__ WB2, const float* __restrict__ b2,
    float* __restrict__ outp)
{
  __shared__ unsigned short ylds[32*64];
  __shared__ unsigned short hlds[32*128];
  const int l = threadIdx.x;
  const int g = l >> 4, c = l & 15;
  const int P0 = blockIdx.x * 32;
  const int b = P0 / HW;
  const int ijb = P0 - b*HW;

  // att = ao @ Wo + bo + emb
  v4f att[2][4];
  #pragma unroll
  for (int t = 0; t < 4; ++t){
    float bb = bo[c + 16*t];
    #pragma unroll
    for (int m = 0; m < 2; ++m)
      #pragma unroll
      for (int r = 0; r < 4; ++r)
        att[m][t][r] = bb + emb[((size_t)(P0 + m*16 + 4*g + r))*64 + c + 16*t];
  }
  #pragma unroll
  for (int kk = 0; kk < 2; ++kk){
    v8bf a[2];
    #pragma unroll
    for (int m = 0; m < 2; ++m)
      a[m] = *(const v8bf*)(ao + (size_t)(P0 + m*16 + c)*64 + kk*32 + 8*g);
    #pragma unroll
    for (int t = 0; t < 4; ++t){
      v8bf bfr = *(const v8bf*)(WBo + ((size_t)((kk*4 + t)*64 + l))*8);
      att[0][t] = __builtin_amdgcn_mfma_f32_16x16x32_bf16(a[0], bfr, att[0][t], 0, 0, 0);
      att[1][t] = __builtin_amdgcn_mfma_f32_16x16x32_bf16(a[1], bfr, att[1][t], 0, 0, 0);
    }
  }

  // LayerNorm -> ylds (bf16, swizzled)
  float gv[4], bev[4];
  #pragma unroll
  for (int t = 0; t < 4; ++t){ gv[t] = gn[c + 16*t]; bev[t] = bn[c + 16*t]; }
  #pragma unroll
  for (int m = 0; m < 2; ++m){
    float mean[4], inv[4];
    #pragma unroll
    for (int r = 0; r < 4; ++r){
      float s = att[m][0][r] + att[m][1][r] + att[m][2][r] + att[m][3][r];
      s += __shfl_xor(s, 1, 64); s += __shfl_xor(s, 2, 64);
      s += __shfl_xor(s, 4, 64); s += __shfl_xor(s, 8, 64);
      mean[r] = s * (1.f/64.f);
      float d0 = att[m][0][r] - mean[r], d1 = att[m][1][r] - mean[r];
      float d2 = att[m][2][r] - mean[r], d3 = att[m][3][r] - mean[r];
      float vs = d0*d0 + d1*d1 + d2*d2 + d3*d3;
      vs += __shfl_xor(vs, 1, 64); vs += __shfl_xor(vs, 2, 64);
      vs += __shfl_xor(vs, 4, 64); vs += __shfl_xor(vs, 8, 64);
      inv[r] = rsqrtf(vs * (1.f/64.f) + 1e-5f);
    }
    #pragma unroll
    for (int t = 0; t < 4; ++t){
      int c16 = 2*t + (c >> 3);
      #pragma unroll
      for (int r = 0; r < 4; ++r){
        int row = m*16 + 4*g + r;
        float n = (att[m][t][r] - mean[r]) * inv[r] * gv[t] + bev[t];
        ylds[row*64 + (((c16 ^ (row & 7)) << 3) | (c & 7))] = f2bf(n);
      }
    }
  }
  __syncthreads();

  // h = gelu(y @ W1 + b1)  [32 x 128]
  v4f hc[2][8];
  #pragma unroll
  for (int tt = 0; tt < 8; ++tt){
    float bb = b1[c + 16*tt];
    hc[0][tt] = (v4f){bb,bb,bb,bb};
    hc[1][tt] = (v4f){bb,bb,bb,bb};
  }
  #pragma unroll
  for (int kk = 0; kk < 2; ++kk){
    v8bf a[2];
    #pragma unroll
    for (int m = 0; m < 2; ++m){
      int row = m*16 + c;
      a[m] = *(const v8bf*)(ylds + row*64 + (((kk*4 + g) ^ (c & 7)) << 3));
    }
    #pragma unroll
    for (int tt = 0; tt < 8; ++tt){
      v8bf bfr = *(const v8bf*)(WB1 + ((size_t)((kk*8 + tt)*64 + l))*8);
      hc[0][tt] = __builtin_amdgcn_mfma_f32_16x16x32_bf16(a[0], bfr, hc[0][tt], 0, 0, 0);
      hc[1][tt] = __builtin_amdgcn_mfma_f32_16x16x32_bf16(a[1], bfr, hc[1][tt], 0, 0, 0);
    }
  }
  #pragma unroll
  for (int m = 0; m < 2; ++m)
    #pragma unroll
    for (int tt = 0; tt < 8; ++tt){
      int chunk = 2*tt + (c >> 3);
      #pragma unroll
      for (int r = 0; r < 4; ++r){
        int row = m*16 + 4*g + r;
        int swz = (chunk & 8) | ((chunk & 7) ^ (row & 7));
        hlds[row*128 + swz*8 + (c & 7)] = f2bf(gelu_exact(hc[m][tt][r]));
      }
    }
  __syncthreads();

  // x = h @ W2 + b2 + att -> NCHW
  v4f xc[2][4];
  #pragma unroll
  for (int t = 0; t < 4; ++t){
    float bb = b2[c + 16*t];
    #pragma unroll
    for (int m = 0; m < 2; ++m)
      #pragma unroll
      for (int r = 0; r < 4; ++r)
        xc[m][t][r] = bb + att[m][t][r];
  }
  #pragma unroll
  for (int kk = 0; kk < 4; ++kk){
    v8bf a[2];
    #pragma unroll
    for (int m = 0; m < 2; ++m){
      int row = m*16 + c;
      int chunk = 4*kk + g;
      int swz = (chunk & 8) | ((chunk & 7) ^ (row & 7));
      a[m] = *(const v8bf*)(hlds + row*128 + swz*8);
    }
    #pragma unroll
    for (int t = 0; t < 4; ++t){
      v8bf bfr = *(const v8bf*)(WB2 + ((size_t)((kk*4 + t)*64 + l))*8);
      xc[0][t] = __builtin_amdgcn_mfma_f32_16x16x32_bf16(a[0], bfr, xc[0][t], 0, 0, 0);
      xc[1][t] = __builtin_amdgcn_mfma_f32_16x16x32_bf16(a[1], bfr, xc[1][t], 0, 0, 0);
    }
  }
  #pragma unroll
  for (int m = 0; m < 2; ++m)
    #pragma unroll
    for (int t = 0; t < 4; ++t)
      #pragma unroll
      for (int r = 0; r < 4; ++r)
        outp[((size_t)(b*64 + c + 16*t))*HW + ijb + m*16 + 4*g + r] = xc[m][t][r];
}

extern "C" void kernel_launch(void* const* d_in, const int* in_sizes, int n_in,
                              void* d_out, int out_size, void* d_ws, size_t ws_size,
                              hipStream_t stream) {
  const float* xq  = (const float*)d_in[0];
  const float* xkv = (const float*)d_in[1];
  const float* cws = (const float*)d_in[2];
  const float* cbs = (const float*)d_in[3];
  const float* cwl = (const float*)d_in[4];
  const float* cbl = (const float*)d_in[5];
  const float* g_s = (const float*)d_in[6];
  const float* b_s = (const float*)d_in[7];
  const float* g_l = (const float*)d_in[8];
  const float* b_l = (const float*)d_in[9];
  const float* Wq  = (const float*)d_in[10];
  const float* bq  = (const float*)d_in[11];
  const float* Wk  = (const float*)d_in[12];
  const float* bk  = (const float*)d_in[13];
  const float* Wv  = (const float*)d_in[14];
  const float* bv  = (const float*)d_in[15];
  const float* Wo  = (const float*)d_in[16];
  const float* bo  = (const float*)d_in[17];
  const float* rpb = (const float*)d_in[18];
  const float* g_n = (const float*)d_in[19];
  const float* b_n = (const float*)d_in[20];
  const float* W1  = (const float*)d_in[21];
  const float* b1  = (const float*)d_in[22];
  const float* W2  = (const float*)d_in[23];
  const float* b2  = (const float*)d_in[24];

  unsigned short* xTq  = (unsigned short*)d_ws;          // NPIX*64
  unsigned short* xTkv = xTq  + (size_t)NPIX*64;
  unsigned short* WBs  = xTkv + (size_t)NPIX*64;         // 36864
  unsigned short* WBl  = WBs  + 36864;
  unsigned short* WBq  = WBl  + 36864;                   // 4096
  unsigned short* WBk  = WBq  + 4096;
  unsigned short* WBv  = WBk  + 4096;
  unsigned short* WBo  = WBv  + 4096;
  unsigned short* WB1  = WBo  + 4096;                    // 8192
  unsigned short* WB2  = WB1  + 8192;                    // 8192
  unsigned short* qb   = WB2  + 8192;                    // NPIX*64 bf16
  unsigned short* kb   = qb   + (size_t)NPIX*64;
  unsigned short* vb   = kb   + (size_t)NPIX*64;
  unsigned short* aob  = vb   + (size_t)NPIX*64;         // NPIX*64 bf16
  float* emb  = (float*)(aob + (size_t)NPIX*64);         // NPIX*64 f32
  float* rpb2 = emb + (size_t)NPIX*64;                   // 676 f32

  hipLaunchKernelGGL(k_prep_x, dim3(NPIX/64), dim3(256), 0, stream, xq,  xTq);
  hipLaunchKernelGGL(k_prep_x, dim3(NPIX/64), dim3(256), 0, stream, xkv, xTkv);
  hipLaunchKernelGGL(k_prep_wconv, dim3(18), dim3(256), 0, stream, cws, WBs);
  hipLaunchKernelGGL(k_prep_wconv, dim3(18), dim3(256), 0, stream, cwl, WBl);
  hipLaunchKernelGGL(k_prep_wlinG, dim3(2), dim3(256), 0, stream, Wq, WBq, 64, 512);
  hipLaunchKernelGGL(k_prep_wlinG, dim3(2), dim3(256), 0, stream, Wk, WBk, 64, 512);
  hipLaunchKernelGGL(k_prep_wlinG, dim3(2), dim3(256), 0, stream, Wv, WBv, 64, 512);
  hipLaunchKernelGGL(k_prep_wlinG, dim3(2), dim3(256), 0, stream, Wo, WBo, 64, 512);
  hipLaunchKernelGGL(k_prep_wlinG, dim3(4), dim3(256), 0, stream, W1, WB1, 128, 1024);
  hipLaunchKernelGGL(k_prep_wlinG, dim3(4), dim3(256), 0, stream, W2, WB2, 64, 1024);
  hipLaunchKernelGGL(k_prep_rpb, dim3(3), dim3(256), 0, stream, rpb, rpb2);

  hipLaunchKernelGGL(k_conv_mfma, dim3(NPIX/32), dim3(64), 0, stream,
      xTq, WBs, cbs, g_s, b_s, WBq, bq, (const unsigned short*)nullptr, (const float*)nullptr,
      qb, (unsigned short*)nullptr, (float*)nullptr, 0);

  hipLaunchKernelGGL(k_conv_mfma, dim3(NPIX/32), dim3(64), 0, stream,
      xTkv, WBl, cbl, g_l, b_l, WBk, bk, WBv, bv,
      kb, vb, emb, 1);

  hipLaunchKernelGGL(k_natten_mfma, dim3(NPIX/16), dim3(256), 0, stream,
      qb, kb, vb, rpb2, aob);

  hipLaunchKernelGGL(k_out_mfma, dim3(NPIX/32), dim3(64), 0, stream,
      aob, emb, WBo, bo, g_n, b_n, WB1, b1, WB2, b2, (float*)d_out);
}

// Round 6
// 84.807 us; speedup vs baseline: 6.4452x; 1.4404x over previous
//
#include <hip/hip_runtime.h>
#include <math.h>

#define SS 112
#define HW (SS*SS)
#define NPIX (2*HW)   // B*S*S = 25088

typedef __bf16 v8bf __attribute__((ext_vector_type(8)));
typedef short  v8s  __attribute__((ext_vector_type(8)));
typedef float  v4f  __attribute__((ext_vector_type(4)));

__device__ __forceinline__ unsigned short f2bf(float f){
  unsigned u = __builtin_bit_cast(unsigned, f);
  u = (u + 0x7fffu + ((u >> 16) & 1u)) >> 16;
  return (unsigned short)u;
}
__device__ __forceinline__ v8bf zero8(){
  v8s z = {0,0,0,0,0,0,0,0};
  return __builtin_bit_cast(v8bf, z);
}
__device__ __forceinline__ float gelu_exact(float x){
  return 0.5f * x * (1.0f + erff(x * 0.7071067811865476f));
}

// ---- helpers for weight fragment packing ----
__device__ __forceinline__ void pack_wconv(const float* __restrict__ w,
                                           unsigned short* __restrict__ WB, int idx){
  int lane = idx & 63, tslot = (idx >> 6) & 3, kk = idx >> 8;
  int tap = kk >> 1;
  int ic0 = ((kk & 1) << 5) + ((lane >> 4) << 3);
  int oc  = tslot*16 + (lane & 15);
  union { unsigned short u[8]; uint4 q; } pk;
  #pragma unroll
  for (int i = 0; i < 8; ++i) pk.u[i] = f2bf(w[(oc*64 + ic0 + i)*9 + tap]);
  ((uint4*)WB)[idx] = pk.q;
}
__device__ __forceinline__ void pack_wlin(const float* __restrict__ W,
                                          unsigned short* __restrict__ WB,
                                          int N, int idx){
  int lane = idx & 63;
  int tmp = idx >> 6;
  int tiles = N >> 4;
  int tslot = tmp % tiles;
  int kk = tmp / tiles;
  int k0 = kk*32 + ((lane >> 4) << 3);
  int oc = tslot*16 + (lane & 15);
  union { unsigned short u[8]; uint4 q; } pk;
  #pragma unroll
  for (int i = 0; i < 8; ++i) pk.u[i] = f2bf(W[(size_t)(k0 + i)*N + oc]);
  ((uint4*)WB)[idx] = pk.q;
}

// ------------- one kernel: all weight preps + rpb scale ---------------------
__global__ __launch_bounds__(256) void k_prep_all(
    const float* __restrict__ cws, const float* __restrict__ cwl,
    const float* __restrict__ Wq, const float* __restrict__ Wk,
    const float* __restrict__ Wv, const float* __restrict__ Wo,
    const float* __restrict__ W1, const float* __restrict__ W2,
    const float* __restrict__ rpb,
    unsigned short* __restrict__ WBs, unsigned short* __restrict__ WBl,
    unsigned short* __restrict__ WBq, unsigned short* __restrict__ WBk,
    unsigned short* __restrict__ WBv, unsigned short* __restrict__ WBo,
    unsigned short* __restrict__ WB1, unsigned short* __restrict__ WB2,
    float* __restrict__ rpb2)
{
  const int blk = blockIdx.x, t = threadIdx.x;
  if      (blk < 18) pack_wconv(cws, WBs, blk*256 + t);
  else if (blk < 36) pack_wconv(cwl, WBl, (blk-18)*256 + t);
  else if (blk < 38) pack_wlin(Wq, WBq, 64,  (blk-36)*256 + t);
  else if (blk < 40) pack_wlin(Wk, WBk, 64,  (blk-38)*256 + t);
  else if (blk < 42) pack_wlin(Wv, WBv, 64,  (blk-40)*256 + t);
  else if (blk < 44) pack_wlin(Wo, WBo, 64,  (blk-42)*256 + t);
  else if (blk < 48) pack_wlin(W1, WB1, 128, (blk-44)*256 + t);
  else if (blk < 52) pack_wlin(W2, WB2, 64,  (blk-48)*256 + t);
  else {
    int idx = (blk-52)*256 + t;
    if (idx < 4*169) rpb2[idx] = rpb[idx] * 1.4426950408889634f;
  }
}

// ---------------- prep: NCHW fp32 -> [pixel][c] bf16 (both inputs) ----------
__global__ __launch_bounds__(256) void k_prep_x2(const float* __restrict__ xq,
                                                 const float* __restrict__ xkv,
                                                 unsigned short* __restrict__ xTq,
                                                 unsigned short* __restrict__ xTkv){
  __shared__ float tile[64][68];
  const int t = threadIdx.x;
  const int inst = blockIdx.x >= (NPIX/64) ? 1 : 0;    // 392 blocks per instance
  const float* x = inst ? xkv : xq;
  unsigned short* xT = inst ? xTkv : xTq;
  const int base = (blockIdx.x - inst*(NPIX/64)) * 64;
  const int b = base / HW;
  const int r0 = base - b*HW;
  {
    const int c = t >> 2, xo = (t & 3) << 4;
    const float* src = x + ((size_t)(b*64 + c))*HW + r0 + xo;
    float4 v0 = ((const float4*)src)[0];
    float4 v1 = ((const float4*)src)[1];
    float4 v2 = ((const float4*)src)[2];
    float4 v3 = ((const float4*)src)[3];
    float* dst = &tile[c][xo];
    ((float4*)dst)[0] = v0; ((float4*)dst)[1] = v1;
    ((float4*)dst)[2] = v2; ((float4*)dst)[3] = v3;
  }
  __syncthreads();
  {
    const int px = t >> 2, co = (t & 3) << 4;
    union { unsigned short u[16]; uint4 q[2]; } pk;
    #pragma unroll
    for (int i = 0; i < 16; ++i) pk.u[i] = f2bf(tile[co + i][px]);
    uint4* dst = (uint4*)(xT + ((size_t)(base + px))*64 + co);
    dst[0] = pk.q[0]; dst[1] = pk.q[1];
  }
}

// --------- fused conv(3x3, MFMA) + LayerNorm + projection(s) ---------------
// Both conv instances in one launch. 4 waves/block, 16 px/wave, per-wave LDS.
__global__ __launch_bounds__(256) void k_conv_all(
    const unsigned short* __restrict__ xTq, const unsigned short* __restrict__ xTkv,
    const unsigned short* __restrict__ WBs, const unsigned short* __restrict__ WBl,
    const float* __restrict__ cbs, const float* __restrict__ g_s, const float* __restrict__ b_s,
    const float* __restrict__ cbl, const float* __restrict__ g_l, const float* __restrict__ b_l,
    const unsigned short* __restrict__ WBq, const float* __restrict__ bq_,
    const unsigned short* __restrict__ WBk, const float* __restrict__ bk_,
    const unsigned short* __restrict__ WBv, const float* __restrict__ bv_,
    unsigned short* __restrict__ qb, unsigned short* __restrict__ kb,
    unsigned short* __restrict__ vT, float* __restrict__ emb)
{
  __shared__ unsigned short nlds[4][16*64];
  const int tid = threadIdx.x;
  const int wid = tid >> 6, l = tid & 63;
  const int g = l >> 4, c = l & 15;
  const int HALF = NPIX/64;                        // 392 blocks per instance
  const int inst = blockIdx.x >= HALF ? 1 : 0;
  const int P0 = ((blockIdx.x - inst*HALF)*4 + wid) * 16;

  const unsigned short* xT  = inst ? xTkv : xTq;
  const unsigned short* WBc = inst ? WBl : WBs;
  const float* cb    = inst ? cbl : cbs;
  const float* gamma = inst ? g_l : g_s;
  const float* beta  = inst ? b_l : b_s;

  const int p = P0 + c;                            // A-row pixel for this lane
  const int b = p / HW, r = p - b*HW;
  const int py = r / SS, pxx = r - py*SS;
  const int pb64 = b*HW;

  float cbv[4], gv[4], bev[4];
  #pragma unroll
  for (int t = 0; t < 4; ++t){
    cbv[t] = cb[c + 16*t]; gv[t] = gamma[c + 16*t]; bev[t] = beta[c + 16*t];
  }

  v4f acc[4];
  #pragma unroll
  for (int t = 0; t < 4; ++t) acc[t] = (v4f){cbv[t], cbv[t], cbv[t], cbv[t]};

  const int icg = g << 3;
  #pragma unroll
  for (int kk = 0; kk < 18; ++kk){
    const int tap = kk >> 1;
    const int dy = tap/3 - 1, dx = tap - (tap/3)*3 - 1;
    const int icof = ((kk & 1) << 5) + icg;
    int yy = py + dy, xx = pxx + dx;
    bool ok = ((unsigned)yy < SS) && ((unsigned)xx < SS);
    v8bf a = zero8();
    if (ok) a = *(const v8bf*)(xT + ((size_t)(pb64 + yy*SS + xx))*64 + icof);
    #pragma unroll
    for (int t = 0; t < 4; ++t){
      v8bf bfr = *(const v8bf*)(WBc + ((size_t)((kk*4 + t)*64 + l))*8);
      acc[t] = __builtin_amdgcn_mfma_f32_16x16x32_bf16(a, bfr, acc[t], 0, 0, 0);
    }
  }

  if (inst){
    #pragma unroll
    for (int t = 0; t < 4; ++t)
      #pragma unroll
      for (int r2 = 0; r2 < 4; ++r2)
        emb[((size_t)(P0 + 4*g + r2))*64 + c + 16*t] = acc[t][r2];
  }

  // LayerNorm per pixel (row = 4g+r, channels across 16-lane group x 4 tiles)
  {
    float mean[4], inv[4];
    #pragma unroll
    for (int r2 = 0; r2 < 4; ++r2){
      float s = acc[0][r2] + acc[1][r2] + acc[2][r2] + acc[3][r2];
      s += __shfl_xor(s, 1, 64); s += __shfl_xor(s, 2, 64);
      s += __shfl_xor(s, 4, 64); s += __shfl_xor(s, 8, 64);
      mean[r2] = s * (1.f/64.f);
      float d0 = acc[0][r2] - mean[r2], d1 = acc[1][r2] - mean[r2];
      float d2 = acc[2][r2] - mean[r2], d3 = acc[3][r2] - mean[r2];
      float vs = d0*d0 + d1*d1 + d2*d2 + d3*d3;
      vs += __shfl_xor(vs, 1, 64); vs += __shfl_xor(vs, 2, 64);
      vs += __shfl_xor(vs, 4, 64); vs += __shfl_xor(vs, 8, 64);
      inv[r2] = rsqrtf(vs * (1.f/64.f) + 1e-5f);
    }
    #pragma unroll
    for (int t = 0; t < 4; ++t){
      int c16 = 2*t + (c >> 3);
      #pragma unroll
      for (int r2 = 0; r2 < 4; ++r2){
        int row = 4*g + r2;
        float n = (acc[t][r2] - mean[r2]) * inv[r2] * gv[t] + bev[t];
        nlds[wid][row*64 + (((c16 ^ (row & 7)) << 3) | (c & 7))] = f2bf(n);
      }
    }
  }
  // no barrier: per-wave LDS region, wave-synchronous exchange

  #pragma unroll
  for (int which = 0; which < 2; ++which){
    if (which == 1 && !inst) break;
    const unsigned short* WB = which ? WBv : (inst ? WBk : WBq);
    const float* bias        = which ? bv_ : (inst ? bk_ : bq_);

    float pb[4];
    #pragma unroll
    for (int t = 0; t < 4; ++t) pb[t] = bias[c + 16*t];
    v4f pa[4];
    #pragma unroll
    for (int t = 0; t < 4; ++t) pa[t] = (v4f){pb[t], pb[t], pb[t], pb[t]};

    #pragma unroll
    for (int kk = 0; kk < 2; ++kk){
      v8bf av = *(const v8bf*)(nlds[wid] + c*64 + (((kk*4 + g) ^ (c & 7)) << 3));
      #pragma unroll
      for (int t = 0; t < 4; ++t){
        v8bf bfr = *(const v8bf*)(WB + ((size_t)((kk*4 + t)*64 + l))*8);
        pa[t] = __builtin_amdgcn_mfma_f32_16x16x32_bf16(av, bfr, pa[t], 0, 0, 0);
      }
    }
    if (which == 0){
      unsigned short* outp = inst ? kb : qb;
      #pragma unroll
      for (int t = 0; t < 4; ++t)
        #pragma unroll
        for (int r2 = 0; r2 < 4; ++r2)
          outp[((size_t)(P0 + 4*g + r2))*64 + c + 16*t] = f2bf(pa[t][r2]);
    } else {
      // V stored transposed: vT[ch][pixel]
      #pragma unroll
      for (int t = 0; t < 4; ++t)
        #pragma unroll
        for (int r2 = 0; r2 < 4; ++r2)
          vT[(size_t)(c + 16*t)*NPIX + (P0 + 4*g + r2)] = f2bf(pa[t][r2]);
    }
  }
}

// ---------------- neighborhood attention via MFMA ---------------------------
// Block = 4 waves = 4 heads of one 16-pixel row segment.
// Key window: 7 rows x 32 cols starting at (si, aj) with aj 8-aligned.
// QK tile tau: A-row slot rho holds key kx = 8*(rho>>2) + 4*(tau&1) + (rho&3),
// ky = tau>>1. QK C-fragment == PV A-fragment (bit-identical).
__global__ __launch_bounds__(256) void k_natten_mfma(
    const unsigned short* __restrict__ q, const unsigned short* __restrict__ k,
    const unsigned short* __restrict__ vT, const float* __restrict__ rpb2,
    unsigned short* __restrict__ out)
{
  const int l = threadIdx.x & 63;
  const int h = threadIdx.x >> 6;
  const int p0 = blockIdx.x * 16;
  const int b = p0 / HW, r0 = p0 - b*HW;
  const int i = r0 / SS, j0 = r0 - i*SS;
  const int c = l & 15, g = l >> 4;

  const int si = min(max(i - 3, 0), SS - 7);
  const int aj = (min(max(j0 - 3, 0), SS - 22)) & ~7;   // 8-aligned window start
  const int oi = si - i + 6;                            // bias row offset
  const int pbase = b*HW;

  const int j   = j0 + c;
  const int sjp = min(max(j - 3, 0), SS - 7);
  const int adj = 8*g + (aj - sjp);                     // valid: 0 <= adj+cc <= 6
  const int e8  = 8*g + (aj - j + 6);                   // rj = e8 + cc

  // Q B-frag: col = pixel c, k = dh = 8g+i (g>=2 zero-padded)
  v8bf bq = zero8();
  if (g < 2) bq = *(const v8bf*)(q + (size_t)(p0 + c)*64 + h*16 + 8*g);

  // ---- QK^T: 14 MFMA tiles -> 56 logits/lane ----
  float lt[14][4];
  const int arow = 8*(c >> 2) + (c & 3);
  #pragma unroll
  for (int tau = 0; tau < 14; ++tau){
    const int t = tau >> 1;
    int kpix = pbase + (si + t)*SS + aj + arow + 4*(tau & 1);
    kpix = min(kpix, NPIX - 1);
    v8bf ak = zero8();
    if (g < 2) ak = *(const v8bf*)(k + (size_t)kpix*64 + h*16 + 8*g);
    v4f a0 = {0.f,0.f,0.f,0.f};
    a0 = __builtin_amdgcn_mfma_f32_16x16x32_bf16(ak, bq, a0, 0, 0, 0);
    lt[tau][0]=a0[0]; lt[tau][1]=a0[1]; lt[tau][2]=a0[2]; lt[tau][3]=a0[3];
  }

  // ---- mask + bias (log2 domain) + softmax ----
  const float SC = 0.3606737602222409f;       // 0.25/ln2
  float mx = -3e38f;
  #pragma unroll
  for (int tau = 0; tau < 14; ++tau){
    const int t = tau >> 1;
    const float* bt = rpb2 + h*169 + (t + oi)*13;
    #pragma unroll
    for (int r = 0; r < 4; ++r){
      const int cc = 4*(tau & 1) + r;
      int rj = min(max(e8 + cc, 0), 12);
      float bias = bt[rj];
      bool valid = (unsigned)(adj + cc) <= 6u;
      float lg = fmaf(lt[tau][r], SC, bias);
      lt[tau][r] = valid ? lg : -1e30f;
      mx = fmaxf(mx, lt[tau][r]);
    }
  }
  mx = fmaxf(mx, __shfl_xor(mx, 16, 64));
  mx = fmaxf(mx, __shfl_xor(mx, 32, 64));
  float es = 0.f;
  #pragma unroll
  for (int tau = 0; tau < 14; ++tau)
    #pragma unroll
    for (int r = 0; r < 4; ++r){
      float p = exp2f(lt[tau][r] - mx);
      lt[tau][r] = p;
      es += p;
    }
  es += __shfl_xor(es, 16, 64);
  es += __shfl_xor(es, 32, 64);
  const float inv = 1.0f / es;

  // ---- PV: 7 MFMA tiles (K=32 keys each), V from transposed layout ----
  const unsigned short* vrow = vT + (size_t)(h*16 + c)*NPIX;
  v4f oacc = {0.f,0.f,0.f,0.f};
  #pragma unroll
  for (int t = 0; t < 7; ++t){
    union { unsigned short u[8]; v8bf bf; } pa;
    #pragma unroll
    for (int r = 0; r < 4; ++r){
      pa.u[r]     = f2bf(lt[2*t][r]   * inv);
      pa.u[4 + r] = f2bf(lt[2*t+1][r] * inv);
    }
    int vpixb = pbase + (si + t)*SS + aj + 8*g;   // 8-aligned -> 16B-aligned load
    vpixb = min(vpixb, NPIX - 8);
    v8bf bv = *(const v8bf*)(vrow + vpixb);
    oacc = __builtin_amdgcn_mfma_f32_16x16x32_bf16(pa.bf, bv, oacc, 0, 0, 0);
  }

  // C: row = pixel 4g+r, col = dh = c
  #pragma unroll
  for (int r = 0; r < 4; ++r)
    out[(size_t)(p0 + 4*g + r)*64 + h*16 + c] = f2bf(oacc[r]);
}

// ------- Wo proj + residual + LN + MLP (exact GELU) + residual, NCHW -------
// 4 waves/block, 16 px/wave, per-wave LDS, no barriers.
__global__ __launch_bounds__(256) void k_out_mfma(
    const unsigned short* __restrict__ ao, const float* __restrict__ emb,
    const unsigned short* __restrict__ WBo, const float* __restrict__ bo,
    const float* __restrict__ gn, const float* __restrict__ bn,
    const unsigned short* __restrict__ WB1, const float* __restrict__ b1,
    const unsigned short* __restrict__ WB2, const float* __restrict__ b2,
    float* __restrict__ outp)
{
  __shared__ unsigned short ylds[4][16*64];
  __shared__ unsigned short hlds[4][16*128];
  const int tid = threadIdx.x;
  const int wid = tid >> 6, l = tid & 63;
  const int g = l >> 4, c = l & 15;
  const int P0 = (blockIdx.x*4 + wid) * 16;
  const int b = P0 / HW;
  const int ijb = P0 - b*HW;

  // att = ao @ Wo + bo + emb
  v4f att[4];
  #pragma unroll
  for (int t = 0; t < 4; ++t){
    float bb = bo[c + 16*t];
    #pragma unroll
    for (int r = 0; r < 4; ++r)
      att[t][r] = bb + emb[((size_t)(P0 + 4*g + r))*64 + c + 16*t];
  }
  #pragma unroll
  for (int kk = 0; kk < 2; ++kk){
    v8bf a = *(const v8bf*)(ao + (size_t)(P0 + c)*64 + kk*32 + 8*g);
    #pragma unroll
    for (int t = 0; t < 4; ++t){
      v8bf bfr = *(const v8bf*)(WBo + ((size_t)((kk*4 + t)*64 + l))*8);
      att[t] = __builtin_amdgcn_mfma_f32_16x16x32_bf16(a, bfr, att[t], 0, 0, 0);
    }
  }

  // LayerNorm -> ylds (bf16, swizzled)
  {
    float gv[4], bev[4];
    #pragma unroll
    for (int t = 0; t < 4; ++t){ gv[t] = gn[c + 16*t]; bev[t] = bn[c + 16*t]; }
    float mean[4], inv[4];
    #pragma unroll
    for (int r = 0; r < 4; ++r){
      float s = att[0][r] + att[1][r] + att[2][r] + att[3][r];
      s += __shfl_xor(s, 1, 64); s += __shfl_xor(s, 2, 64);
      s += __shfl_xor(s, 4, 64); s += __shfl_xor(s, 8, 64);
      mean[r] = s * (1.f/64.f);
      float d0 = att[0][r] - mean[r], d1 = att[1][r] - mean[r];
      float d2 = att[2][r] - mean[r], d3 = att[3][r] - mean[r];
      float vs = d0*d0 + d1*d1 + d2*d2 + d3*d3;
      vs += __shfl_xor(vs, 1, 64); vs += __shfl_xor(vs, 2, 64);
      vs += __shfl_xor(vs, 4, 64); vs += __shfl_xor(vs, 8, 64);
      inv[r] = rsqrtf(vs * (1.f/64.f) + 1e-5f);
    }
    #pragma unroll
    for (int t = 0; t < 4; ++t){
      int c16 = 2*t + (c >> 3);
      #pragma unroll
      for (int r = 0; r < 4; ++r){
        int row = 4*g + r;
        float n = (att[t][r] - mean[r]) * inv[r] * gv[t] + bev[t];
        ylds[wid][row*64 + (((c16 ^ (row & 7)) << 3) | (c & 7))] = f2bf(n);
      }
    }
  }

  // h = gelu(y @ W1 + b1)  [16 x 128]
  v4f hc[8];
  #pragma unroll
  for (int tt = 0; tt < 8; ++tt){
    float bb = b1[c + 16*tt];
    hc[tt] = (v4f){bb,bb,bb,bb};
  }
  #pragma unroll
  for (int kk = 0; kk < 2; ++kk){
    v8bf a = *(const v8bf*)(ylds[wid] + c*64 + (((kk*4 + g) ^ (c & 7)) << 3));
    #pragma unroll
    for (int tt = 0; tt < 8; ++tt){
      v8bf bfr = *(const v8bf*)(WB1 + ((size_t)((kk*8 + tt)*64 + l))*8);
      hc[tt] = __builtin_amdgcn_mfma_f32_16x16x32_bf16(a, bfr, hc[tt], 0, 0, 0);
    }
  }
  #pragma unroll
  for (int tt = 0; tt < 8; ++tt){
    int chunk = 2*tt + (c >> 3);
    #pragma unroll
    for (int r = 0; r < 4; ++r){
      int row = 4*g + r;
      int swz = (chunk & 8) | ((chunk & 7) ^ (row & 7));
      hlds[wid][row*128 + swz*8 + (c & 7)] = f2bf(gelu_exact(hc[tt][r]));
    }
  }

  // x = h @ W2 + b2 + att -> NCHW
  v4f xc[4];
  #pragma unroll
  for (int t = 0; t < 4; ++t){
    float bb = b2[c + 16*t];
    #pragma unroll
    for (int r = 0; r < 4; ++r)
      xc[t][r] = bb + att[t][r];
  }
  #pragma unroll
  for (int kk = 0; kk < 4; ++kk){
    int chunk = 4*kk + g;
    int swz = (chunk & 8) | ((chunk & 7) ^ (c & 7));
    v8bf a = *(const v8bf*)(hlds[wid] + c*128 + swz*8);
    #pragma unroll
    for (int t = 0; t < 4; ++t){
      v8bf bfr = *(const v8bf*)(WB2 + ((size_t)((kk*4 + t)*64 + l))*8);
      xc[t] = __builtin_amdgcn_mfma_f32_16x16x32_bf16(a, bfr, xc[t], 0, 0, 0);
    }
  }
  #pragma unroll
  for (int t = 0; t < 4; ++t)
    #pragma unroll
    for (int r = 0; r < 4; ++r)
      outp[((size_t)(b*64 + c + 16*t))*HW + ijb + 4*g + r] = xc[t][r];
}

extern "C" void kernel_launch(void* const* d_in, const int* in_sizes, int n_in,
                              void* d_out, int out_size, void* d_ws, size_t ws_size,
                              hipStream_t stream) {
  const float* xq  = (const float*)d_in[0];
  const float* xkv = (const float*)d_in[1];
  const float* cws = (const float*)d_in[2];
  const float* cbs = (const float*)d_in[3];
  const float* cwl = (const float*)d_in[4];
  const float* cbl = (const float*)d_in[5];
  const float* g_s = (const float*)d_in[6];
  const float* b_s = (const float*)d_in[7];
  const float* g_l = (const float*)d_in[8];
  const float* b_l = (const float*)d_in[9];
  const float* Wq  = (const float*)d_in[10];
  const float* bq  = (const float*)d_in[11];
  const float* Wk  = (const float*)d_in[12];
  const float* bk  = (const float*)d_in[13];
  const float* Wv  = (const float*)d_in[14];
  const float* bv  = (const float*)d_in[15];
  const float* Wo  = (const float*)d_in[16];
  const float* bo  = (const float*)d_in[17];
  const float* rpb = (const float*)d_in[18];
  const float* g_n = (const float*)d_in[19];
  const float* b_n = (const float*)d_in[20];
  const float* W1  = (const float*)d_in[21];
  const float* b1  = (const float*)d_in[22];
  const float* W2  = (const float*)d_in[23];
  const float* b2  = (const float*)d_in[24];

  unsigned short* xTq  = (unsigned short*)d_ws;          // NPIX*64
  unsigned short* xTkv = xTq  + (size_t)NPIX*64;
  unsigned short* WBs  = xTkv + (size_t)NPIX*64;         // 36864
  unsigned short* WBl  = WBs  + 36864;
  unsigned short* WBq  = WBl  + 36864;                   // 4096
  unsigned short* WBk  = WBq  + 4096;
  unsigned short* WBv  = WBk  + 4096;
  unsigned short* WBo  = WBv  + 4096;
  unsigned short* WB1  = WBo  + 4096;                    // 8192
  unsigned short* WB2  = WB1  + 8192;                    // 8192
  unsigned short* qb   = WB2  + 8192;                    // NPIX*64 bf16
  unsigned short* kb   = qb   + (size_t)NPIX*64;
  unsigned short* vT   = kb   + (size_t)NPIX*64;         // transposed [64][NPIX]
  unsigned short* aob  = vT   + (size_t)NPIX*64;         // NPIX*64 bf16
  float* emb  = (float*)(aob + (size_t)NPIX*64);         // NPIX*64 f32
  float* rpb2 = emb + (size_t)NPIX*64;                   // 676 f32

  hipLaunchKernelGGL(k_prep_all, dim3(55), dim3(256), 0, stream,
      cws, cwl, Wq, Wk, Wv, Wo, W1, W2, rpb,
      WBs, WBl, WBq, WBk, WBv, WBo, WB1, WB2, rpb2);

  hipLaunchKernelGGL(k_prep_x2, dim3(NPIX/32), dim3(256), 0, stream,
      xq, xkv, xTq, xTkv);

  hipLaunchKernelGGL(k_conv_all, dim3(NPIX/32), dim3(256), 0, stream,
      xTq, xTkv, WBs, WBl,
      cbs, g_s, b_s, cbl, g_l, b_l,
      WBq, bq, WBk, bk, WBv, bv,
      qb, kb, vT, emb);

  hipLaunchKernelGGL(k_natten_mfma, dim3(NPIX/16), dim3(256), 0, stream,
      qb, kb, vT, rpb2, aob);

  hipLaunchKernelGGL(k_out_mfma, dim3(NPIX/64), dim3(256), 0, stream,
      aob, emb, WBo, bo, g_n, b_n, WB1, b1, WB2, b2, (float*)d_out);
}

// Round 7
// 75.013 us; speedup vs baseline: 7.2868x; 1.1306x over previous
//
#include <hip/hip_runtime.h>
#include <math.h>

#define SS 112
#define HW (SS*SS)
#define NPIX (2*HW)   // B*S*S = 25088

typedef __bf16 v8bf __attribute__((ext_vector_type(8)));
typedef short  v8s  __attribute__((ext_vector_type(8)));
typedef float  v4f  __attribute__((ext_vector_type(4)));

__device__ __forceinline__ unsigned short f2bf(float f){
  unsigned u = __builtin_bit_cast(unsigned, f);
  u = (u + 0x7fffu + ((u >> 16) & 1u)) >> 16;
  return (unsigned short)u;
}
__device__ __forceinline__ unsigned cvt_pk_bf16(float lo, float hi){
  unsigned r;
  asm("v_cvt_pk_bf16_f32 %0, %1, %2" : "=v"(r) : "v"(lo), "v"(hi));
  return r;
}
__device__ __forceinline__ v8bf zero8(){
  v8s z = {0,0,0,0,0,0,0,0};
  return __builtin_bit_cast(v8bf, z);
}
// tanh-form GELU: x * s/(s+1), s = exp2(2.3021178*(x + 0.044715 x^3))
__device__ __forceinline__ float gelu_fast(float x){
  float u = fmaf(0.044715f*x, x, 1.0f);
  float z = fminf(2.3021178f * x * u, 80.0f);
  float s = exp2f(z);
  return x * s * __builtin_amdgcn_rcpf(s + 1.0f);
}

// ---- weight fragment packing helpers ----
__device__ __forceinline__ void pack_wconv(const float* __restrict__ w,
                                           unsigned short* __restrict__ WB, int idx){
  int lane = idx & 63, tslot = (idx >> 6) & 3, kk = idx >> 8;
  int tap = kk >> 1;
  int ic0 = ((kk & 1) << 5) + ((lane >> 4) << 3);
  int oc  = tslot*16 + (lane & 15);
  union { unsigned short u[8]; uint4 q; } pk;
  #pragma unroll
  for (int i = 0; i < 8; ++i) pk.u[i] = f2bf(w[(oc*64 + ic0 + i)*9 + tap]);
  ((uint4*)WB)[idx] = pk.q;
}
__device__ __forceinline__ void pack_wlin(const float* __restrict__ W,
                                          unsigned short* __restrict__ WB,
                                          int N, int idx){
  int lane = idx & 63;
  int tmp = idx >> 6;
  int tiles = N >> 4;
  int tslot = tmp % tiles;
  int kk = tmp / tiles;
  int k0 = kk*32 + ((lane >> 4) << 3);
  int oc = tslot*16 + (lane & 15);
  union { unsigned short u[8]; uint4 q; } pk;
  #pragma unroll
  for (int i = 0; i < 8; ++i) pk.u[i] = f2bf(W[(size_t)(k0 + i)*N + oc]);
  ((uint4*)WB)[idx] = pk.q;
}

// ------------- one kernel: all weight preps + rpb + x transpose -------------
__global__ __launch_bounds__(256) void k_prep(
    const float* __restrict__ xq, const float* __restrict__ xkv,
    const float* __restrict__ cws, const float* __restrict__ cwl,
    const float* __restrict__ Wq, const float* __restrict__ Wk,
    const float* __restrict__ Wv, const float* __restrict__ Wo,
    const float* __restrict__ W1, const float* __restrict__ W2,
    const float* __restrict__ rpb,
    unsigned short* __restrict__ WBs, unsigned short* __restrict__ WBl,
    unsigned short* __restrict__ WBq, unsigned short* __restrict__ WBk,
    unsigned short* __restrict__ WBv, unsigned short* __restrict__ WBo,
    unsigned short* __restrict__ WB1, unsigned short* __restrict__ WB2,
    float* __restrict__ rpb2g,
    unsigned short* __restrict__ xTq, unsigned short* __restrict__ xTkv)
{
  __shared__ float tile[64][68];
  const int blk = blockIdx.x, t = threadIdx.x;
  if (blk < 55){
    if      (blk < 18) pack_wconv(cws, WBs, blk*256 + t);
    else if (blk < 36) pack_wconv(cwl, WBl, (blk-18)*256 + t);
    else if (blk < 38) pack_wlin(Wq, WBq, 64,  (blk-36)*256 + t);
    else if (blk < 40) pack_wlin(Wk, WBk, 64,  (blk-38)*256 + t);
    else if (blk < 42) pack_wlin(Wv, WBv, 64,  (blk-40)*256 + t);
    else if (blk < 44) pack_wlin(Wo, WBo, 64,  (blk-42)*256 + t);
    else if (blk < 48) pack_wlin(W1, WB1, 128, (blk-44)*256 + t);
    else if (blk < 52) pack_wlin(W2, WB2, 64,  (blk-48)*256 + t);
    else {
      int idx = (blk-52)*256 + t;
      if (idx < 4*169) rpb2g[idx] = rpb[idx] * 1.4426950408889634f;
    }
    return;
  }
  const int blk2 = blk - 55;
  const int inst = blk2 >= (NPIX/64) ? 1 : 0;
  const float* x = inst ? xkv : xq;
  unsigned short* xT = inst ? xTkv : xTq;
  const int base = (blk2 - inst*(NPIX/64)) * 64;
  const int b = base / HW;
  const int r0 = base - b*HW;
  {
    const int c = t >> 2, xo = (t & 3) << 4;
    const float* src = x + ((size_t)(b*64 + c))*HW + r0 + xo;
    float4 v0 = ((const float4*)src)[0];
    float4 v1 = ((const float4*)src)[1];
    float4 v2 = ((const float4*)src)[2];
    float4 v3 = ((const float4*)src)[3];
    float* dst = &tile[c][xo];
    ((float4*)dst)[0] = v0; ((float4*)dst)[1] = v1;
    ((float4*)dst)[2] = v2; ((float4*)dst)[3] = v3;
  }
  __syncthreads();
  {
    const int px = t >> 2, co = (t & 3) << 4;
    union { unsigned short u[16]; uint4 q[2]; } pk;
    #pragma unroll
    for (int i = 0; i < 16; ++i) pk.u[i] = f2bf(tile[co + i][px]);
    uint4* dst = (uint4*)(xT + ((size_t)(base + px))*64 + co);
    dst[0] = pk.q[0]; dst[1] = pk.q[1];
  }
}

// --------- fused conv(3x3, MFMA) + LayerNorm + projection(s) ---------------
// Both conv instances in one launch. 4 waves/block, 16 px/wave, per-wave LDS.
__global__ __launch_bounds__(256) void k_conv_all(
    const unsigned short* __restrict__ xTq, const unsigned short* __restrict__ xTkv,
    const unsigned short* __restrict__ WBs, const unsigned short* __restrict__ WBl,
    const float* __restrict__ cbs, const float* __restrict__ g_s, const float* __restrict__ b_s,
    const float* __restrict__ cbl, const float* __restrict__ g_l, const float* __restrict__ b_l,
    const unsigned short* __restrict__ WBq, const float* __restrict__ bq_,
    const unsigned short* __restrict__ WBk, const float* __restrict__ bk_,
    const unsigned short* __restrict__ WBv, const float* __restrict__ bv_,
    unsigned short* __restrict__ qb, unsigned short* __restrict__ kb,
    unsigned short* __restrict__ vT, float* __restrict__ emb)
{
  __shared__ unsigned short nlds[4][16*64];
  const int tid = threadIdx.x;
  const int wid = tid >> 6, l = tid & 63;
  const int g = l >> 4, c = l & 15;
  const int HALF = NPIX/64;
  const int inst = blockIdx.x >= HALF ? 1 : 0;
  const int P0 = ((blockIdx.x - inst*HALF)*4 + wid) * 16;

  const unsigned short* xT  = inst ? xTkv : xTq;
  const unsigned short* WBc = inst ? WBl : WBs;
  const float* cb    = inst ? cbl : cbs;
  const float* gamma = inst ? g_l : g_s;
  const float* beta  = inst ? b_l : b_s;

  const int p = P0 + c;
  const int b = p / HW, r = p - b*HW;
  const int py = r / SS, pxx = r - py*SS;
  const int pb64 = b*HW;

  float cbv[4], gv[4], bev[4];
  #pragma unroll
  for (int t = 0; t < 4; ++t){
    cbv[t] = cb[c + 16*t]; gv[t] = gamma[c + 16*t]; bev[t] = beta[c + 16*t];
  }

  v4f acc[4];
  #pragma unroll
  for (int t = 0; t < 4; ++t) acc[t] = (v4f){cbv[t], cbv[t], cbv[t], cbv[t]};

  const int icg = g << 3;
  #pragma unroll
  for (int kk = 0; kk < 18; ++kk){
    const int tap = kk >> 1;
    const int dy = tap/3 - 1, dx = tap - (tap/3)*3 - 1;
    const int icof = ((kk & 1) << 5) + icg;
    int yy = py + dy, xx = pxx + dx;
    bool ok = ((unsigned)yy < SS) && ((unsigned)xx < SS);
    v8bf a = zero8();
    if (ok) a = *(const v8bf*)(xT + ((size_t)(pb64 + yy*SS + xx))*64 + icof);
    #pragma unroll
    for (int t = 0; t < 4; ++t){
      v8bf bfr = *(const v8bf*)(WBc + ((size_t)((kk*4 + t)*64 + l))*8);
      acc[t] = __builtin_amdgcn_mfma_f32_16x16x32_bf16(a, bfr, acc[t], 0, 0, 0);
    }
  }

  if (inst){
    #pragma unroll
    for (int t = 0; t < 4; ++t)
      #pragma unroll
      for (int r2 = 0; r2 < 4; ++r2)
        emb[((size_t)(P0 + 4*g + r2))*64 + c + 16*t] = acc[t][r2];
  }

  // LayerNorm per pixel
  {
    float mean[4], inv[4];
    #pragma unroll
    for (int r2 = 0; r2 < 4; ++r2){
      float s = acc[0][r2] + acc[1][r2] + acc[2][r2] + acc[3][r2];
      s += __shfl_xor(s, 1, 64); s += __shfl_xor(s, 2, 64);
      s += __shfl_xor(s, 4, 64); s += __shfl_xor(s, 8, 64);
      mean[r2] = s * (1.f/64.f);
      float d0 = acc[0][r2] - mean[r2], d1 = acc[1][r2] - mean[r2];
      float d2 = acc[2][r2] - mean[r2], d3 = acc[3][r2] - mean[r2];
      float vs = d0*d0 + d1*d1 + d2*d2 + d3*d3;
      vs += __shfl_xor(vs, 1, 64); vs += __shfl_xor(vs, 2, 64);
      vs += __shfl_xor(vs, 4, 64); vs += __shfl_xor(vs, 8, 64);
      inv[r2] = rsqrtf(vs * (1.f/64.f) + 1e-5f);
    }
    #pragma unroll
    for (int t = 0; t < 4; ++t){
      int c16 = 2*t + (c >> 3);
      #pragma unroll
      for (int r2 = 0; r2 < 4; r2 += 2){
        int row0 = 4*g + r2, row1 = row0 + 1;
        float n0 = (acc[t][r2]   - mean[r2])   * inv[r2]   * gv[t] + bev[t];
        float n1 = (acc[t][r2+1] - mean[r2+1]) * inv[r2+1] * gv[t] + bev[t];
        unsigned w = cvt_pk_bf16(n0, n1);
        nlds[wid][row0*64 + (((c16 ^ (row0 & 7)) << 3) | (c & 7))] = (unsigned short)(w & 0xffffu);
        nlds[wid][row1*64 + (((c16 ^ (row1 & 7)) << 3) | (c & 7))] = (unsigned short)(w >> 16);
      }
    }
  }
  // no barrier: per-wave LDS region, wave-synchronous exchange

  #pragma unroll
  for (int which = 0; which < 2; ++which){
    if (which == 1 && !inst) break;
    const unsigned short* WB = which ? WBv : (inst ? WBk : WBq);
    const float* bias        = which ? bv_ : (inst ? bk_ : bq_);

    float pb[4];
    #pragma unroll
    for (int t = 0; t < 4; ++t) pb[t] = bias[c + 16*t];
    v4f pa[4];
    #pragma unroll
    for (int t = 0; t < 4; ++t) pa[t] = (v4f){pb[t], pb[t], pb[t], pb[t]};

    #pragma unroll
    for (int kk = 0; kk < 2; ++kk){
      v8bf av = *(const v8bf*)(nlds[wid] + c*64 + (((kk*4 + g) ^ (c & 7)) << 3));
      #pragma unroll
      for (int t = 0; t < 4; ++t){
        v8bf bfr = *(const v8bf*)(WB + ((size_t)((kk*4 + t)*64 + l))*8);
        pa[t] = __builtin_amdgcn_mfma_f32_16x16x32_bf16(av, bfr, pa[t], 0, 0, 0);
      }
    }
    if (which == 0){
      unsigned short* outp = inst ? kb : qb;
      #pragma unroll
      for (int t = 0; t < 4; ++t)
        #pragma unroll
        for (int r2 = 0; r2 < 4; r2 += 2){
          unsigned w = cvt_pk_bf16(pa[t][r2], pa[t][r2+1]);
          outp[((size_t)(P0 + 4*g + r2))*64 + c + 16*t]     = (unsigned short)(w & 0xffffu);
          outp[((size_t)(P0 + 4*g + r2+1))*64 + c + 16*t]   = (unsigned short)(w >> 16);
        }
    } else {
      // V stored transposed: vT[ch][pixel]; pixel addresses adjacent -> dword pairs
      #pragma unroll
      for (int t = 0; t < 4; ++t){
        uint2 w2;
        w2.x = cvt_pk_bf16(pa[t][0], pa[t][1]);
        w2.y = cvt_pk_bf16(pa[t][2], pa[t][3]);
        *(uint2*)(vT + (size_t)(c + 16*t)*NPIX + (P0 + 4*g)) = w2;
      }
    }
  }
}

// ---------------- neighborhood attention via MFMA ---------------------------
// Block = 4 waves = 4 heads of one 16-pixel row segment.
// Key window: 7 rows x 32 cols starting at (si, aj) with aj 8-aligned.
// QK tile tau: A-row slot rho holds key kx = 8*(rho>>2) + 4*(tau&1) + (rho&3),
// ky = tau>>1. QK C-fragment == PV A-fragment (bit-identical).
__global__ __launch_bounds__(256) void k_natten_mfma(
    const unsigned short* __restrict__ q, const unsigned short* __restrict__ k,
    const unsigned short* __restrict__ vT, const float* __restrict__ rpb2g,
    unsigned short* __restrict__ out)
{
  const int l = threadIdx.x & 63;
  const int h = threadIdx.x >> 6;
  const int p0 = blockIdx.x * 16;
  const int b = p0 / HW, r0 = p0 - b*HW;
  const int i = r0 / SS, j0 = r0 - i*SS;
  const int c = l & 15, g = l >> 4;

  const int si = min(max(i - 3, 0), SS - 7);
  const int aj = (min(max(j0 - 3, 0), SS - 22)) & ~7;   // 8-aligned window start
  const int oi = si - i + 6;
  const int pbase = b*HW;

  const int j   = j0 + c;
  const int sjp = min(max(j - 3, 0), SS - 7);
  const int adj = 8*g + (aj - sjp);                     // valid: 0 <= adj+cc <= 6
  // guarded bias base: bp[t*13+cc] == rpb2g[h*169 + (t+oi)*13 + (e8+cc)]
  const float* bp = rpb2g + h*169 + oi*13 + (8*g + aj - j + 6);

  v8bf bq = zero8();
  if (g < 2) bq = *(const v8bf*)(q + (size_t)(p0 + c)*64 + h*16 + 8*g);

  // ---- QK^T: 14 MFMA tiles -> 56 logits/lane ----
  float lt[14][4];
  const int arow = 8*(c >> 2) + (c & 3);
  #pragma unroll
  for (int tau = 0; tau < 14; ++tau){
    const int t = tau >> 1;
    int kpix = pbase + (si + t)*SS + aj + arow + 4*(tau & 1);
    kpix = min(kpix, NPIX - 1);
    v8bf ak = zero8();
    if (g < 2) ak = *(const v8bf*)(k + (size_t)kpix*64 + h*16 + 8*g);
    v4f a0 = {0.f,0.f,0.f,0.f};
    a0 = __builtin_amdgcn_mfma_f32_16x16x32_bf16(ak, bq, a0, 0, 0, 0);
    lt[tau][0]=a0[0]; lt[tau][1]=a0[1]; lt[tau][2]=a0[2]; lt[tau][3]=a0[3];
  }

  // ---- mask + bias (log2 domain) + softmax, 4 parallel chains ----
  const float SC = 0.3606737602222409f;       // 0.25/ln2
  float mx4[4] = {-3e38f,-3e38f,-3e38f,-3e38f};
  #pragma unroll
  for (int tau = 0; tau < 14; ++tau){
    const int t = tau >> 1;
    #pragma unroll
    for (int r = 0; r < 4; ++r){
      const int cc = 4*(tau & 1) + r;
      float bias = bp[t*13 + cc];             // imm-offset load; garbage if masked
      float lg = fmaf(lt[tau][r], SC, bias);
      lt[tau][r] = ((unsigned)(adj + cc) <= 6u) ? lg : -1e30f;
      mx4[r] = fmaxf(mx4[r], lt[tau][r]);
    }
  }
  float mx = fmaxf(fmaxf(mx4[0], mx4[1]), fmaxf(mx4[2], mx4[3]));
  mx = fmaxf(mx, __shfl_xor(mx, 16, 64));
  mx = fmaxf(mx, __shfl_xor(mx, 32, 64));
  float es4[4] = {0.f,0.f,0.f,0.f};
  #pragma unroll
  for (int tau = 0; tau < 14; ++tau)
    #pragma unroll
    for (int r = 0; r < 4; ++r){
      float p = exp2f(lt[tau][r] - mx);
      lt[tau][r] = p;
      es4[r] += p;
    }
  float es = (es4[0] + es4[1]) + (es4[2] + es4[3]);
  es += __shfl_xor(es, 16, 64);
  es += __shfl_xor(es, 32, 64);
  const float inv = 1.0f / es;

  // ---- PV: 7 MFMA tiles (K=32 keys each), V from transposed layout ----
  const unsigned short* vrow = vT + (size_t)(h*16 + c)*NPIX;
  v4f oacc = {0.f,0.f,0.f,0.f};
  #pragma unroll
  for (int t = 0; t < 7; ++t){
    union { unsigned w[4]; v8bf bf; } pa;
    pa.w[0] = cvt_pk_bf16(lt[2*t][0]*inv,   lt[2*t][1]*inv);
    pa.w[1] = cvt_pk_bf16(lt[2*t][2]*inv,   lt[2*t][3]*inv);
    pa.w[2] = cvt_pk_bf16(lt[2*t+1][0]*inv, lt[2*t+1][1]*inv);
    pa.w[3] = cvt_pk_bf16(lt[2*t+1][2]*inv, lt[2*t+1][3]*inv);
    int vpixb = pbase + (si + t)*SS + aj + 8*g;
    vpixb = min(vpixb, NPIX - 8);
    v8bf bv = *(const v8bf*)(vrow + vpixb);
    oacc = __builtin_amdgcn_mfma_f32_16x16x32_bf16(pa.bf, bv, oacc, 0, 0, 0);
  }

  // C: row = pixel 4g+r, col = dh = c
  #pragma unroll
  for (int r = 0; r < 4; r += 2){
    unsigned w = cvt_pk_bf16(oacc[r], oacc[r+1]);
    out[(size_t)(p0 + 4*g + r)*64 + h*16 + c]     = (unsigned short)(w & 0xffffu);
    out[(size_t)(p0 + 4*g + r+1)*64 + h*16 + c]   = (unsigned short)(w >> 16);
  }
}

// ------- Wo proj + residual + LN + MLP (fast GELU) + residual, NCHW --------
// 4 waves/block, 16 px/wave, per-wave LDS, no barriers.
__global__ __launch_bounds__(256) void k_out_mfma(
    const unsigned short* __restrict__ ao, const float* __restrict__ emb,
    const unsigned short* __restrict__ WBo, const float* __restrict__ bo,
    const float* __restrict__ gn, const float* __restrict__ bn,
    const unsigned short* __restrict__ WB1, const float* __restrict__ b1,
    const unsigned short* __restrict__ WB2, const float* __restrict__ b2,
    float* __restrict__ outp)
{
  __shared__ unsigned short ylds[4][16*64];
  __shared__ unsigned short hlds[4][16*128];
  const int tid = threadIdx.x;
  const int wid = tid >> 6, l = tid & 63;
  const int g = l >> 4, c = l & 15;
  const int P0 = (blockIdx.x*4 + wid) * 16;
  const int b = P0 / HW;
  const int ijb = P0 - b*HW;

  // att = ao @ Wo + bo + emb
  v4f att[4];
  #pragma unroll
  for (int t = 0; t < 4; ++t){
    float bb = bo[c + 16*t];
    #pragma unroll
    for (int r = 0; r < 4; ++r)
      att[t][r] = bb + emb[((size_t)(P0 + 4*g + r))*64 + c + 16*t];
  }
  #pragma unroll
  for (int kk = 0; kk < 2; ++kk){
    v8bf a = *(const v8bf*)(ao + (size_t)(P0 + c)*64 + kk*32 + 8*g);
    #pragma unroll
    for (int t = 0; t < 4; ++t){
      v8bf bfr = *(const v8bf*)(WBo + ((size_t)((kk*4 + t)*64 + l))*8);
      att[t] = __builtin_amdgcn_mfma_f32_16x16x32_bf16(a, bfr, att[t], 0, 0, 0);
    }
  }

  // LayerNorm -> ylds (bf16, swizzled)
  {
    float gv[4], bev[4];
    #pragma unroll
    for (int t = 0; t < 4; ++t){ gv[t] = gn[c + 16*t]; bev[t] = bn[c + 16*t]; }
    float mean[4], inv[4];
    #pragma unroll
    for (int r = 0; r < 4; ++r){
      float s = att[0][r] + att[1][r] + att[2][r] + att[3][r];
      s += __shfl_xor(s, 1, 64); s += __shfl_xor(s, 2, 64);
      s += __shfl_xor(s, 4, 64); s += __shfl_xor(s, 8, 64);
      mean[r] = s * (1.f/64.f);
      float d0 = att[0][r] - mean[r], d1 = att[1][r] - mean[r];
      float d2 = att[2][r] - mean[r], d3 = att[3][r] - mean[r];
      float vs = d0*d0 + d1*d1 + d2*d2 + d3*d3;
      vs += __shfl_xor(vs, 1, 64); vs += __shfl_xor(vs, 2, 64);
      vs += __shfl_xor(vs, 4, 64); vs += __shfl_xor(vs, 8, 64);
      inv[r] = rsqrtf(vs * (1.f/64.f) + 1e-5f);
    }
    #pragma unroll
    for (int t = 0; t < 4; ++t){
      int c16 = 2*t + (c >> 3);
      #pragma unroll
      for (int r = 0; r < 4; r += 2){
        int row0 = 4*g + r, row1 = row0 + 1;
        float n0 = (att[t][r]   - mean[r])   * inv[r]   * gv[t] + bev[t];
        float n1 = (att[t][r+1] - mean[r+1]) * inv[r+1] * gv[t] + bev[t];
        unsigned w = cvt_pk_bf16(n0, n1);
        ylds[wid][row0*64 + (((c16 ^ (row0 & 7)) << 3) | (c & 7))] = (unsigned short)(w & 0xffffu);
        ylds[wid][row1*64 + (((c16 ^ (row1 & 7)) << 3) | (c & 7))] = (unsigned short)(w >> 16);
      }
    }
  }

  // h = gelu(y @ W1 + b1)  [16 x 128]
  v4f hc[8];
  #pragma unroll
  for (int tt = 0; tt < 8; ++tt){
    float bb = b1[c + 16*tt];
    hc[tt] = (v4f){bb,bb,bb,bb};
  }
  #pragma unroll
  for (int kk = 0; kk < 2; ++kk){
    v8bf a = *(const v8bf*)(ylds[wid] + c*64 + (((kk*4 + g) ^ (c & 7)) << 3));
    #pragma unroll
    for (int tt = 0; tt < 8; ++tt){
      v8bf bfr = *(const v8bf*)(WB1 + ((size_t)((kk*8 + tt)*64 + l))*8);
      hc[tt] = __builtin_amdgcn_mfma_f32_16x16x32_bf16(a, bfr, hc[tt], 0, 0, 0);
    }
  }
  #pragma unroll
  for (int tt = 0; tt < 8; ++tt){
    int chunk = 2*tt + (c >> 3);
    #pragma unroll
    for (int r = 0; r < 4; r += 2){
      int row0 = 4*g + r, row1 = row0 + 1;
      int swz0 = (chunk & 8) | ((chunk & 7) ^ (row0 & 7));
      int swz1 = (chunk & 8) | ((chunk & 7) ^ (row1 & 7));
      unsigned w = cvt_pk_bf16(gelu_fast(hc[tt][r]), gelu_fast(hc[tt][r+1]));
      hlds[wid][row0*128 + swz0*8 + (c & 7)] = (unsigned short)(w & 0xffffu);
      hlds[wid][row1*128 + swz1*8 + (c & 7)] = (unsigned short)(w >> 16);
    }
  }

  // x = h @ W2 + b2 + att -> NCHW
  v4f xc[4];
  #pragma unroll
  for (int t = 0; t < 4; ++t){
    float bb = b2[c + 16*t];
    #pragma unroll
    for (int r = 0; r < 4; ++r)
      xc[t][r] = bb + att[t][r];
  }
  #pragma unroll
  for (int kk = 0; kk < 4; ++kk){
    int chunk = 4*kk + g;
    int swz = (chunk & 8) | ((chunk & 7) ^ (c & 7));
    v8bf a = *(const v8bf*)(hlds[wid] + c*128 + swz*8);
    #pragma unroll
    for (int t = 0; t < 4; ++t){
      v8bf bfr = *(const v8bf*)(WB2 + ((size_t)((kk*4 + t)*64 + l))*8);
      xc[t] = __builtin_amdgcn_mfma_f32_16x16x32_bf16(a, bfr, xc[t], 0, 0, 0);
    }
  }
  #pragma unroll
  for (int t = 0; t < 4; ++t)
    #pragma unroll
    for (int r = 0; r < 4; ++r)
      outp[((size_t)(b*64 + c + 16*t))*HW + ijb + 4*g + r] = xc[t][r];
}

extern "C" void kernel_launch(void* const* d_in, const int* in_sizes, int n_in,
                              void* d_out, int out_size, void* d_ws, size_t ws_size,
                              hipStream_t stream) {
  const float* xq  = (const float*)d_in[0];
  const float* xkv = (const float*)d_in[1];
  const float* cws = (const float*)d_in[2];
  const float* cbs = (const float*)d_in[3];
  const float* cwl = (const float*)d_in[4];
  const float* cbl = (const float*)d_in[5];
  const float* g_s = (const float*)d_in[6];
  const float* b_s = (const float*)d_in[7];
  const float* g_l = (const float*)d_in[8];
  const float* b_l = (const float*)d_in[9];
  const float* Wq  = (const float*)d_in[10];
  const float* bq  = (const float*)d_in[11];
  const float* Wk  = (const float*)d_in[12];
  const float* bk  = (const float*)d_in[13];
  const float* Wv  = (const float*)d_in[14];
  const float* bv  = (const float*)d_in[15];
  const float* Wo  = (const float*)d_in[16];
  const float* bo  = (const float*)d_in[17];
  const float* rpb = (const float*)d_in[18];
  const float* g_n = (const float*)d_in[19];
  const float* b_n = (const float*)d_in[20];
  const float* W1  = (const float*)d_in[21];
  const float* b1  = (const float*)d_in[22];
  const float* W2  = (const float*)d_in[23];
  const float* b2  = (const float*)d_in[24];

  unsigned short* xTq  = (unsigned short*)d_ws;          // NPIX*64
  unsigned short* xTkv = xTq  + (size_t)NPIX*64;
  unsigned short* WBs  = xTkv + (size_t)NPIX*64;         // 36864
  unsigned short* WBl  = WBs  + 36864;
  unsigned short* WBq  = WBl  + 36864;                   // 4096
  unsigned short* WBk  = WBq  + 4096;
  unsigned short* WBv  = WBk  + 4096;
  unsigned short* WBo  = WBv  + 4096;
  unsigned short* WB1  = WBo  + 4096;                    // 8192
  unsigned short* WB2  = WB1  + 8192;                    // 8192
  unsigned short* qb   = WB2  + 8192;                    // NPIX*64 bf16
  unsigned short* kb   = qb   + (size_t)NPIX*64;
  unsigned short* vT   = kb   + (size_t)NPIX*64;         // transposed [64][NPIX]
  unsigned short* aob  = vT   + (size_t)NPIX*64;         // NPIX*64 bf16
  float* emb   = (float*)(aob + (size_t)NPIX*64);        // NPIX*64 f32
  float* rpb2a = emb + (size_t)NPIX*64;                  // 1216 f32 (guarded)
  float* rpb2g = rpb2a + 64;                             // table at +64, guards both sides

  hipLaunchKernelGGL(k_prep, dim3(55 + NPIX/32), dim3(256), 0, stream,
      xq, xkv, cws, cwl, Wq, Wk, Wv, Wo, W1, W2, rpb,
      WBs, WBl, WBq, WBk, WBv, WBo, WB1, WB2, rpb2g, xTq, xTkv);

  hipLaunchKernelGGL(k_conv_all, dim3(NPIX/32), dim3(256), 0, stream,
      xTq, xTkv, WBs, WBl,
      cbs, g_s, b_s, cbl, g_l, b_l,
      WBq, bq, WBk, bk, WBv, bv,
      qb, kb, vT, emb);

  hipLaunchKernelGGL(k_natten_mfma, dim3(NPIX/16), dim3(256), 0, stream,
      qb, kb, vT, rpb2g, aob);

  hipLaunchKernelGGL(k_out_mfma, dim3(NPIX/64), dim3(256), 0, stream,
      aob, emb, WBo, bo, g_n, b_n, WB1, b1, WB2, b2, (float*)d_out);
}